// Round 12
// baseline (2129.880 us; speedup 1.0000x reference)
//
#include <hip/hip_runtime.h>
#include <math.h>

#define TD 192
#define HD 48
#define KSEL 128
#define QB 4

// Map float to orderable unsigned: a > b (float) <=> f2o(a) > f2o(b)
__device__ __forceinline__ unsigned f2o(float f) {
  unsigned u = __float_as_uint(f);
  return (u & 0x80000000u) ? ~u : (u | 0x80000000u);
}
__device__ __forceinline__ float o2f(unsigned u) {
  unsigned v = (u & 0x80000000u) ? (u & 0x7fffffffu) : ~u;
  return __uint_as_float(v);
}

// 2D sinusoidal positional encoding, matches reference _pos_enc.
__global__ void pe_kernel(float* __restrict__ pe, int W) {
  int n = blockIdx.x;
  int t = threadIdx.x;                      // 0..191
  const float c = -0.09594104554885301f;    // -ln(10000)/96
  float val;
  if (t < 96) {
    float dv = expf((float)t * c);
    val = sinf((float)(n % W) * dv);
  } else {
    float dv = expf((float)(t - 96) * c);
    val = cosf((float)(n / W) * dv);
  }
  pe[n * TD + t] = val;
}

// Tiled QKV projection: 64 tokens x 192 channels per block; feat tile in LDS;
// blockIdx.y = type (0:Q+pe, 1:K+pe -> Kt transposed, 2:V). Coalesced writes
// for ALL outputs (r11 lesson: per-token scatter of Kt amplified WRITE 3.3x).
__global__ __launch_bounds__(256) void qkv_tiled(
    const float* __restrict__ feat1, const float* __restrict__ feat2,
    const float* __restrict__ qw, const float* __restrict__ qb,
    const float* __restrict__ kw, const float* __restrict__ kb,
    const float* __restrict__ vw, const float* __restrict__ vb,
    const float* __restrict__ pe,
    float* __restrict__ Q, float* __restrict__ Kt, float* __restrict__ V,
    int C, int N) {
  __shared__ float ftile[64][64];           // 16 KB chunk of feat
  const int type = blockIdx.y;
  const int tid = threadIdx.x;
  const int gtok = blockIdx.x * 64;
  const int b = gtok / N, n0 = gtok - b * N;
  const float* feat = (type == 0) ? feat1 : feat2;
  const float* wsel = (type == 0) ? qw : (type == 1) ? kw : vw;
  const float* bsel = (type == 0) ? qb : (type == 1) ? kb : vb;
  const int cg = tid >> 4, tg = tid & 15;
  const int ch0 = cg * 12, t0 = tg * 4;     // 12 channels x 4 tokens per thread

  float4 z = make_float4(0.f, 0.f, 0.f, 0.f);
  float4 a0 = z, a1 = z, a2 = z, a3 = z, a4 = z, a5 = z,
         a6 = z, a7 = z, a8 = z, a9 = z, a10 = z, a11 = z;

  for (int c0 = 0; c0 < C; c0 += 64) {
#pragma unroll
    for (int rep = 0; rep < 4; ++rep) {
      int off = rep * 1024 + tid * 4;
      int r = off >> 6, cc = off & 63;
      *reinterpret_cast<float4*>(&ftile[r][cc]) =
          *reinterpret_cast<const float4*>(&feat[((size_t)(b * C + c0 + r)) * N + n0 + cc]);
    }
    __syncthreads();
#pragma unroll 8
    for (int k = 0; k < 64; ++k) {
      float4 f4 = *reinterpret_cast<const float4*>(&ftile[k][t0]);
      const float* wr = wsel + (size_t)(c0 + k) * TD + ch0;
      float4 w0 = *reinterpret_cast<const float4*>(wr);
      float4 w1 = *reinterpret_cast<const float4*>(wr + 4);
      float4 w2 = *reinterpret_cast<const float4*>(wr + 8);
#define QFMA(A, WS) A.x = fmaf(WS, f4.x, A.x); A.y = fmaf(WS, f4.y, A.y); \
                    A.z = fmaf(WS, f4.z, A.z); A.w = fmaf(WS, f4.w, A.w);
      QFMA(a0, w0.x) QFMA(a1, w0.y) QFMA(a2, w0.z) QFMA(a3, w0.w)
      QFMA(a4, w1.x) QFMA(a5, w1.y) QFMA(a6, w1.z) QFMA(a7, w1.w)
      QFMA(a8, w2.x) QFMA(a9, w2.y) QFMA(a10, w2.z) QFMA(a11, w2.w)
#undef QFMA
    }
    __syncthreads();
  }
  // bias (per channel, broadcast to 4 tokens)
  {
    float4 b0 = *reinterpret_cast<const float4*>(&bsel[ch0]);
    float4 b1 = *reinterpret_cast<const float4*>(&bsel[ch0 + 4]);
    float4 b2 = *reinterpret_cast<const float4*>(&bsel[ch0 + 8]);
#define BADD(A, S) A.x += S; A.y += S; A.z += S; A.w += S;
    BADD(a0, b0.x) BADD(a1, b0.y) BADD(a2, b0.z) BADD(a3, b0.w)
    BADD(a4, b1.x) BADD(a5, b1.y) BADD(a6, b1.z) BADD(a7, b1.w)
    BADD(a8, b2.x) BADD(a9, b2.y) BADD(a10, b2.z) BADD(a11, b2.w)
#undef BADD
  }
  if (type < 2) {  // + positional encoding (per token row)
#define PEADD(F, TT) { \
    const float* pr = pe + (size_t)(n0 + t0 + (TT)) * TD + ch0; \
    float4 p0 = *reinterpret_cast<const float4*>(pr); \
    float4 p1 = *reinterpret_cast<const float4*>(pr + 4); \
    float4 p2 = *reinterpret_cast<const float4*>(pr + 8); \
    a0.F += p0.x; a1.F += p0.y; a2.F += p0.z; a3.F += p0.w; \
    a4.F += p1.x; a5.F += p1.y; a6.F += p1.z; a7.F += p1.w; \
    a8.F += p2.x; a9.F += p2.y; a10.F += p2.z; a11.F += p2.w; }
    PEADD(x, 0) PEADD(y, 1) PEADD(z, 2) PEADD(w, 3)
#undef PEADD
  }
  if (type == 1) {  // Kt[(b*4+h)*48+d][n] transposed, float4 over tokens
#define KSTORE(A, CI) { int ch = ch0 + (CI); int h = ch / HD, d = ch - h * HD; \
    *reinterpret_cast<float4*>(&Kt[((size_t)(b * 4 + h) * HD + d) * N + n0 + t0]) = A; }
    KSTORE(a0, 0) KSTORE(a1, 1) KSTORE(a2, 2) KSTORE(a3, 3)
    KSTORE(a4, 4) KSTORE(a5, 5) KSTORE(a6, 6) KSTORE(a7, 7)
    KSTORE(a8, 8) KSTORE(a9, 9) KSTORE(a10, 10) KSTORE(a11, 11)
#undef KSTORE
  } else {          // Q / V row-major [token][channel]
    float* out = (type == 0) ? Q : V;
#define RSTORE(F, TT) { \
    float* orow = out + (size_t)(b * N + n0 + t0 + (TT)) * TD + ch0; \
    *reinterpret_cast<float4*>(orow)     = make_float4(a0.F, a1.F, a2.F, a3.F); \
    *reinterpret_cast<float4*>(orow + 4) = make_float4(a4.F, a5.F, a6.F, a7.F); \
    *reinterpret_cast<float4*>(orow + 8) = make_float4(a8.F, a9.F, a10.F, a11.F); }
    RSTORE(x, 0) RSTORE(y, 1) RSTORE(z, 2) RSTORE(w, 3)
#undef RSTORE
  }
}

// ---------------- Stage A ----------------
// Block = (bhloc, 4 queries, key-range of RK). Cooperative score GEMM -> LDS,
// wave w owns query w with RK/64 keys/lane in registers, radix-select
// per-range top-128 with exact lowest-index ties. RK==2048 uses an 11-bit
// first pass with a 2048-bin histogram REUSING the key-staging LDS (f2o keys
// cluster in ~10-20 of 256 top-byte bins -> same-address atomic serialization;
// 2048 bins de-cluster ~8x). FUSE (R==1): per-range top-128 IS the global
// top-128 -> softmax + V-gather inline, no candidates.
template <int N, int RK, bool FUSE>
__global__ __launch_bounds__(256) void attnA_kernel(
    const float* __restrict__ Q, const float* __restrict__ Kt,
    unsigned* __restrict__ ckey, unsigned short* __restrict__ cidx,
    const float* __restrict__ V, float* __restrict__ O, int bh0) {
  constexpr int R = N / RK;
  constexpr int NV4 = RK / 256;           // uint4 regs per lane
  constexpr int nq = N / QB;
  constexpr bool BIG = (RK == 2048);
  __shared__ unsigned sb[QB * RK];        // keys; reused as 2048-bin hist (BIG)
  __shared__ float qv[QB][HD];
  __shared__ unsigned hist[4][256];

  const int tid = threadIdx.x;
  const int r = blockIdx.x % R;
  const int qg = (blockIdx.x / R) % nq;
  const int bhloc = blockIdx.x / (R * nq);
  const int bh = bh0 + bhloc;
  const int b = bh >> 2, h = bh & 3;
  const int q0 = qg * QB;
  const float scale = 0.14433756729740643f;  // 1/sqrt(48)

  if (tid < QB * HD) {
    int q = tid / HD, d = tid - q * HD;
    qv[q][d] = Q[((size_t)(b * N + q0 + q)) * TD + h * HD + d];
  }
  __syncthreads();

  const int w = tid >> 6, lane = tid & 63;
  const unsigned long long lanelt = (1ull << lane) - 1ull;
  const float* kt = Kt + ((size_t)(b * 4 + h) * HD) * N + r * RK;

  // ---- score GEMM for this range ----
  for (int j0 = tid * 4; j0 < RK; j0 += 1024) {
    float4 acc[QB];
#pragma unroll
    for (int q = 0; q < QB; ++q) acc[q] = make_float4(0.f, 0.f, 0.f, 0.f);
#pragma unroll
    for (int d4 = 0; d4 < HD; d4 += 4) {
      float4 k0 = *reinterpret_cast<const float4*>(kt + (size_t)(d4 + 0) * N + j0);
      float4 k1 = *reinterpret_cast<const float4*>(kt + (size_t)(d4 + 1) * N + j0);
      float4 k2 = *reinterpret_cast<const float4*>(kt + (size_t)(d4 + 2) * N + j0);
      float4 k3 = *reinterpret_cast<const float4*>(kt + (size_t)(d4 + 3) * N + j0);
#pragma unroll
      for (int q = 0; q < QB; ++q) {
        float4 qq = *reinterpret_cast<const float4*>(&qv[q][d4]);
        acc[q].x = fmaf(qq.x, k0.x, acc[q].x); acc[q].x = fmaf(qq.y, k1.x, acc[q].x);
        acc[q].x = fmaf(qq.z, k2.x, acc[q].x); acc[q].x = fmaf(qq.w, k3.x, acc[q].x);
        acc[q].y = fmaf(qq.x, k0.y, acc[q].y); acc[q].y = fmaf(qq.y, k1.y, acc[q].y);
        acc[q].y = fmaf(qq.z, k2.y, acc[q].y); acc[q].y = fmaf(qq.w, k3.y, acc[q].y);
        acc[q].z = fmaf(qq.x, k0.z, acc[q].z); acc[q].z = fmaf(qq.y, k1.z, acc[q].z);
        acc[q].z = fmaf(qq.z, k2.z, acc[q].z); acc[q].z = fmaf(qq.w, k3.z, acc[q].z);
        acc[q].w = fmaf(qq.x, k0.w, acc[q].w); acc[q].w = fmaf(qq.y, k1.w, acc[q].w);
        acc[q].w = fmaf(qq.z, k2.w, acc[q].w); acc[q].w = fmaf(qq.w, k3.w, acc[q].w);
      }
    }
#pragma unroll
    for (int q = 0; q < QB; ++q) {
      uint4 kk;
      kk.x = f2o(acc[q].x * scale); kk.y = f2o(acc[q].y * scale);
      kk.z = f2o(acc[q].z * scale); kk.w = f2o(acc[q].w * scale);
      *reinterpret_cast<uint4*>(&sb[q * RK + j0]) = kk;
    }
  }
  __syncthreads();

  // ---- per-wave: keys -> registers ----
  uint4 kr[NV4];
#pragma unroll
  for (int i = 0; i < NV4; ++i)
    kr[i] = *reinterpret_cast<const uint4*>(&sb[w * RK + i * 256 + lane * 4]);
  __syncthreads();   // sb may be reused as histogram below

  // ---- radix select: 128th largest within range ----
  unsigned kth = 0u, mask = 0u;
  int rem = KSEL;

  if constexpr (BIG) {
    // pass 1: 11-bit digit, 2048 bins in this wave's region of sb
    unsigned* hw = sb + w * 2048;
#pragma unroll
    for (int i = 0; i < 8; ++i)
      *reinterpret_cast<uint4*>(&hw[i * 256 + lane * 4]) = make_uint4(0, 0, 0, 0);
#pragma unroll
    for (int i = 0; i < NV4; ++i) {
      atomicAdd(&hw[kr[i].x >> 21], 1u); atomicAdd(&hw[kr[i].y >> 21], 1u);
      atomicAdd(&hw[kr[i].z >> 21], 1u); atomicAdd(&hw[kr[i].w >> 21], 1u);
    }
    int loc = 0;
    const int binLo = 2016 - lane * 32;
#pragma unroll
    for (int i = 0; i < 8; ++i) {
      uint4 v4 = *reinterpret_cast<const uint4*>(&hw[binLo + i * 4]);
      loc += (int)(v4.x + v4.y + v4.z + v4.w);
    }
    int incl = loc;
#pragma unroll
    for (int off = 1; off < 64; off <<= 1) {
      int t = __shfl_up(incl, off, 64);
      if (lane >= off) incl += t;
    }
    int c = incl - loc;
    int selidx = -1, selexcl = 0;
    if (rem > c && rem <= c + loc) {
      int cc = c;
      for (int i = 0; i < 32; ++i) {
        int bin = 2047 - lane * 32 - i;
        int v = (int)hw[bin];
        if (selidx < 0 && rem > cc && rem <= cc + v) { selidx = bin; selexcl = cc; }
        cc += v;
      }
    }
    unsigned long long vote = __ballot(selidx >= 0);
    int src = __ffsll((long long)vote) - 1;
    selidx = __shfl(selidx, src, 64);
    selexcl = __shfl(selexcl, src, 64);
    rem -= selexcl;
    kth = (unsigned)selidx << 21;
    mask = 0xFFE00000u;
    // passes 2-4: 7-bit digits, 128 bins in hist[w]
    unsigned* hs = hist[w];
#pragma unroll
    for (int pass = 0; pass < 3; ++pass) {
      const int shift = 14 - pass * 7;
      hs[lane] = 0u; hs[lane + 64] = 0u;
#pragma unroll
      for (int i = 0; i < NV4; ++i) {
        if ((kr[i].x & mask) == kth) atomicAdd(&hs[(kr[i].x >> shift) & 127u], 1u);
        if ((kr[i].y & mask) == kth) atomicAdd(&hs[(kr[i].y >> shift) & 127u], 1u);
        if ((kr[i].z & mask) == kth) atomicAdd(&hs[(kr[i].z >> shift) & 127u], 1u);
        if ((kr[i].w & mask) == kth) atomicAdd(&hs[(kr[i].w >> shift) & 127u], 1u);
      }
      int v0 = (int)hs[127 - lane * 2], v1 = (int)hs[126 - lane * 2];
      int loc2 = v0 + v1;
      int incl2 = loc2;
#pragma unroll
      for (int off = 1; off < 64; off <<= 1) {
        int t = __shfl_up(incl2, off, 64);
        if (lane >= off) incl2 += t;
      }
      int c2 = incl2 - loc2;
      int si = -1, se = 0;
      if (rem > c2 && rem <= c2 + v0) { si = 127 - lane * 2; se = c2; }
      else if (rem > c2 + v0 && rem <= c2 + loc2) { si = 126 - lane * 2; se = c2 + v0; }
      unsigned long long vt = __ballot(si >= 0);
      int sr = __ffsll((long long)vt) - 1;
      si = __shfl(si, sr, 64);
      se = __shfl(se, sr, 64);
      rem -= se;
      kth |= ((unsigned)si << shift);
      mask |= (0x7Fu << shift);
    }
  } else {
    // 4x 8-bit passes, 256 bins (r11-proven path)
    unsigned* hw = hist[w];
#pragma unroll
    for (int shift = 24; shift >= 0; shift -= 8) {
#pragma unroll
      for (int i = 0; i < 4; ++i) hw[lane + i * 64] = 0u;
#pragma unroll
      for (int i = 0; i < NV4; ++i) {
        if ((kr[i].x & mask) == kth) atomicAdd(&hw[(kr[i].x >> shift) & 255u], 1u);
        if ((kr[i].y & mask) == kth) atomicAdd(&hw[(kr[i].y >> shift) & 255u], 1u);
        if ((kr[i].z & mask) == kth) atomicAdd(&hw[(kr[i].z >> shift) & 255u], 1u);
        if ((kr[i].w & mask) == kth) atomicAdd(&hw[(kr[i].w >> shift) & 255u], 1u);
      }
      int v[4], loc = 0;
#pragma unroll
      for (int i = 0; i < 4; ++i) { v[i] = (int)hw[255 - (lane * 4 + i)]; loc += v[i]; }
      int incl = loc;
#pragma unroll
      for (int off = 1; off < 64; off <<= 1) {
        int t = __shfl_up(incl, off, 64);
        if (lane >= off) incl += t;
      }
      int c = incl - loc;
      int selidx = -1, selexcl = 0;
#pragma unroll
      for (int i = 0; i < 4; ++i) {
        if (selidx < 0 && rem > c && rem <= c + v[i]) {
          selidx = 255 - (lane * 4 + i); selexcl = c;
        }
        c += v[i];
      }
      unsigned long long vote = __ballot(selidx >= 0);
      int src = __ffsll((long long)vote) - 1;
      selidx = __shfl(selidx, src, 64);
      selexcl = __shfl(selexcl, src, 64);
      rem -= selexcl;
      kth |= ((unsigned)selidx << shift);
      mask |= (0xFFu << shift);
    }
  }
  const int need_eq = rem;   // boundary slots among ==kth, lowest index first

  if constexpr (FUSE) {
    // wave max for softmax
    unsigned mk = 0u;
#pragma unroll
    for (int i = 0; i < NV4; ++i) {
      unsigned a_ = kr[i].x > kr[i].y ? kr[i].x : kr[i].y;
      unsigned b_ = kr[i].z > kr[i].w ? kr[i].z : kr[i].w;
      a_ = a_ > b_ ? a_ : b_; mk = a_ > mk ? a_ : mk;
    }
    for (int off = 32; off > 0; off >>= 1) {
      unsigned o = (unsigned)__shfl_xor((int)mk, off, 64);
      mk = o > mk ? o : mk;
    }
    const float mx = o2f(mk);

    __shared__ int idxb[4][KSEL];
    __shared__ float wb[4][KSEL];
    int selbase = 0, eqbase = 0;
    float lz = 0.f;
#pragma unroll
    for (int i = 0; i < NV4; ++i) {
      const int jb = i * 256 + lane * 4;
      const unsigned u0 = kr[i].x, u1 = kr[i].y, u2 = kr[i].z, u3 = kr[i].w;
      const bool e0 = (u0 == kth), e1 = (u1 == kth), e2 = (u2 == kth), e3 = (u3 == kth);
      const unsigned long long b0 = __ballot(e0), b1 = __ballot(e1), b2 = __ballot(e2), b3 = __ballot(e3);
      const int eqlt = __popcll(b0 & lanelt) + __popcll(b1 & lanelt) + __popcll(b2 & lanelt) + __popcll(b3 & lanelt);
      int eo = 0;
      const bool s0 = (u0 > kth) || (e0 && (eqbase + eqlt + eo) < need_eq); eo += e0 ? 1 : 0;
      const bool s1 = (u1 > kth) || (e1 && (eqbase + eqlt + eo) < need_eq); eo += e1 ? 1 : 0;
      const bool s2 = (u2 > kth) || (e2 && (eqbase + eqlt + eo) < need_eq); eo += e2 ? 1 : 0;
      const bool s3 = (u3 > kth) || (e3 && (eqbase + eqlt + eo) < need_eq); eo += e3 ? 1 : 0;
      const unsigned long long c0 = __ballot(s0), c1 = __ballot(s1), c2 = __ballot(s2), c3 = __ballot(s3);
      const int sellt = __popcll(c0 & lanelt) + __popcll(c1 & lanelt) + __popcll(c2 & lanelt) + __popcll(c3 & lanelt);
      int so = 0;
      if (s0) { int p = selbase + sellt + so; float e = expf(o2f(u0) - mx); idxb[w][p] = jb + 0; wb[w][p] = e; lz += e; } so += s0 ? 1 : 0;
      if (s1) { int p = selbase + sellt + so; float e = expf(o2f(u1) - mx); idxb[w][p] = jb + 1; wb[w][p] = e; lz += e; } so += s1 ? 1 : 0;
      if (s2) { int p = selbase + sellt + so; float e = expf(o2f(u2) - mx); idxb[w][p] = jb + 2; wb[w][p] = e; lz += e; } so += s2 ? 1 : 0;
      if (s3) { int p = selbase + sellt + so; float e = expf(o2f(u3) - mx); idxb[w][p] = jb + 3; wb[w][p] = e; lz += e; } so += s3 ? 1 : 0;
      eqbase += __popcll(b0) + __popcll(b1) + __popcll(b2) + __popcll(b3);
      selbase += __popcll(c0) + __popcll(c1) + __popcll(c2) + __popcll(c3);
    }
    for (int off = 32; off > 0; off >>= 1) lz += __shfl_xor(lz, off, 64);
    const float rz = 1.f / lz;
    if (lane < HD) {
      float acc = 0.f;
#pragma unroll 4
      for (int p = 0; p < KSEL; ++p) {
        acc = fmaf(wb[w][p], V[((size_t)(b * N + idxb[w][p])) * TD + h * HD + lane], acc);
      }
      O[((size_t)(b * N + q0 + w)) * TD + h * HD + lane] = acc * rz;
    }
  } else {
    // write (key, idx) candidates for stage B
    unsigned* ok = ckey + (((size_t)bhloc * N + q0 + w) * R + r) * KSEL;
    unsigned short* oi = cidx + (((size_t)bhloc * N + q0 + w) * R + r) * KSEL;
    int selbase = 0, eqbase = 0;
#pragma unroll
    for (int i = 0; i < NV4; ++i) {
      const int jb = r * RK + i * 256 + lane * 4;
      const unsigned u0 = kr[i].x, u1 = kr[i].y, u2 = kr[i].z, u3 = kr[i].w;
      const bool e0 = (u0 == kth), e1 = (u1 == kth), e2 = (u2 == kth), e3 = (u3 == kth);
      const unsigned long long b0 = __ballot(e0), b1 = __ballot(e1), b2 = __ballot(e2), b3 = __ballot(e3);
      const int eqlt = __popcll(b0 & lanelt) + __popcll(b1 & lanelt) + __popcll(b2 & lanelt) + __popcll(b3 & lanelt);
      int eo = 0;
      const bool s0 = (u0 > kth) || (e0 && (eqbase + eqlt + eo) < need_eq); eo += e0 ? 1 : 0;
      const bool s1 = (u1 > kth) || (e1 && (eqbase + eqlt + eo) < need_eq); eo += e1 ? 1 : 0;
      const bool s2 = (u2 > kth) || (e2 && (eqbase + eqlt + eo) < need_eq); eo += e2 ? 1 : 0;
      const bool s3 = (u3 > kth) || (e3 && (eqbase + eqlt + eo) < need_eq); eo += e3 ? 1 : 0;
      const unsigned long long c0 = __ballot(s0), c1 = __ballot(s1), c2 = __ballot(s2), c3 = __ballot(s3);
      const int sellt = __popcll(c0 & lanelt) + __popcll(c1 & lanelt) + __popcll(c2 & lanelt) + __popcll(c3 & lanelt);
      int so = 0;
      if (s0) { int p = selbase + sellt + so; ok[p] = u0; oi[p] = (unsigned short)(jb + 0); } so += s0 ? 1 : 0;
      if (s1) { int p = selbase + sellt + so; ok[p] = u1; oi[p] = (unsigned short)(jb + 1); } so += s1 ? 1 : 0;
      if (s2) { int p = selbase + sellt + so; ok[p] = u2; oi[p] = (unsigned short)(jb + 2); } so += s2 ? 1 : 0;
      if (s3) { int p = selbase + sellt + so; ok[p] = u3; oi[p] = (unsigned short)(jb + 3); } so += s3 ? 1 : 0;
      eqbase += __popcll(b0) + __popcll(b1) + __popcll(b2) + __popcll(b3);
      selbase += __popcll(c0) + __popcll(c1) + __popcll(c2) + __popcll(c3);
    }
  }
}

// ---------------- Stage B ----------------
// Wave per query: load CN candidates (ascending global index by construction),
// radix-select global top-128, softmax, gather V.
template <int CN>
__global__ __launch_bounds__(256) void attnB_kernel(
    const unsigned* __restrict__ ckey, const unsigned short* __restrict__ cidx,
    const float* __restrict__ V, float* __restrict__ O, int N, int bh0) {
  constexpr int CL = CN / 64;
  __shared__ unsigned hist[4][256];
  __shared__ int idxb[4][KSEL];
  __shared__ float wb[4][KSEL];

  const int tid = threadIdx.x, w = tid >> 6, lane = tid & 63;
  const unsigned long long lanelt = (1ull << lane) - 1ull;
  const int g = blockIdx.x * 4 + w;
  const int bhloc = g / N;
  const int qi = g - bhloc * N;
  const int bh = bh0 + bhloc;
  const int b = bh >> 2, h = bh & 3;

  unsigned ck[CL], ci[CL];
#pragma unroll
  for (int i = 0; i < CL; ++i) {
    ck[i] = ckey[(size_t)g * CN + i * 64 + lane];
    ci[i] = cidx[(size_t)g * CN + i * 64 + lane];
  }

  unsigned mk = 0u;
#pragma unroll
  for (int i = 0; i < CL; ++i) mk = ck[i] > mk ? ck[i] : mk;
  for (int off = 32; off > 0; off >>= 1) {
    unsigned o = (unsigned)__shfl_xor((int)mk, off, 64);
    mk = o > mk ? o : mk;
  }
  const float mx = o2f(mk);

  unsigned* hw = hist[w];
  unsigned kth = 0u, mask = 0u;
  int rem = KSEL;
#pragma unroll
  for (int shift = 24; shift >= 0; shift -= 8) {
#pragma unroll
    for (int i = 0; i < 4; ++i) hw[lane + i * 64] = 0u;
#pragma unroll
    for (int i = 0; i < CL; ++i)
      if ((ck[i] & mask) == kth) atomicAdd(&hw[(ck[i] >> shift) & 255u], 1u);
    int v[4], loc = 0;
#pragma unroll
    for (int i = 0; i < 4; ++i) { v[i] = (int)hw[255 - (lane * 4 + i)]; loc += v[i]; }
    int incl = loc;
#pragma unroll
    for (int off = 1; off < 64; off <<= 1) {
      int t = __shfl_up(incl, off, 64);
      if (lane >= off) incl += t;
    }
    int c = incl - loc;
    int selidx = -1, selexcl = 0;
#pragma unroll
    for (int i = 0; i < 4; ++i) {
      if (selidx < 0 && rem > c && rem <= c + v[i]) {
        selidx = 255 - (lane * 4 + i); selexcl = c;
      }
      c += v[i];
    }
    unsigned long long vote = __ballot(selidx >= 0);
    int src = __ffsll((long long)vote) - 1;
    selidx = __shfl(selidx, src, 64);
    selexcl = __shfl(selexcl, src, 64);
    rem -= selexcl;
    kth |= ((unsigned)selidx << shift);
    mask |= (0xFFu << shift);
  }
  const int need_eq = rem;

  int selbase = 0, eqbase = 0;
  float lz = 0.f;
#pragma unroll
  for (int i = 0; i < CL; ++i) {
    const unsigned u = ck[i];
    const bool eq = (u == kth);
    const unsigned long long beq = __ballot(eq);
    const int eqrank = eqbase + __popcll(beq & lanelt);
    const bool sel = (u > kth) || (eq && eqrank < need_eq);
    const unsigned long long bsel = __ballot(sel);
    const int pos = selbase + __popcll(bsel & lanelt);
    if (sel) {
      float e = expf(o2f(u) - mx);
      idxb[w][pos] = (int)ci[i];
      wb[w][pos] = e;
      lz += e;
    }
    eqbase += __popcll(beq);
    selbase += __popcll(bsel);
  }
  for (int off = 32; off > 0; off >>= 1) lz += __shfl_xor(lz, off, 64);
  const float rz = 1.f / lz;

  if (lane < HD) {
    float acc = 0.f;
#pragma unroll 4
    for (int p = 0; p < KSEL; ++p) {
      acc = fmaf(wb[w][p], V[((size_t)(b * N + idxb[w][p])) * TD + h * HD + lane], acc);
    }
    O[((size_t)(b * N + qi)) * TD + h * HD + lane] = acc * rz;
  }
}

// out[b, t, n] = O[b, n, :] . ow[:, t] + ob[t]; 16-token tile (r11-proven).
#define OTOK 16
__global__ __launch_bounds__(256) void oproj_kernel(
    const float* __restrict__ O, const float* __restrict__ ow,
    const float* __restrict__ ob, float* __restrict__ out, int N) {
  __shared__ float otile[OTOK][TD + 1];
  const int tid = threadIdx.x;
  const int nt = N / OTOK;
  const int b = blockIdx.x / nt;
  const int n0 = (blockIdx.x % nt) * OTOK;
  const float* obase = O + ((size_t)(b * N + n0)) * TD;
  for (int idx = tid * 4; idx < OTOK * TD; idx += 1024) {
    float4 v = *reinterpret_cast<const float4*>(obase + idx);
    int r = idx / TD, c = idx - r * TD;
    otile[r][c] = v.x; otile[r][c + 1] = v.y; otile[r][c + 2] = v.z; otile[r][c + 3] = v.w;
  }
  __syncthreads();
  const int nl = tid & 15;
  const int ts = (tid >> 4) * 12;
  float a0 = 0.f, a1 = 0.f, a2 = 0.f, a3 = 0.f, a4 = 0.f, a5 = 0.f,
        a6 = 0.f, a7 = 0.f, a8 = 0.f, a9 = 0.f, a10 = 0.f, a11 = 0.f;
  for (int c = 0; c < TD; ++c) {
    float oval = otile[nl][c];
    const float* wr = ow + c * TD + ts;
    float4 w0 = *reinterpret_cast<const float4*>(wr);
    float4 w1 = *reinterpret_cast<const float4*>(wr + 4);
    float4 w2 = *reinterpret_cast<const float4*>(wr + 8);
    a0 = fmaf(oval, w0.x, a0); a1 = fmaf(oval, w0.y, a1);
    a2 = fmaf(oval, w0.z, a2); a3 = fmaf(oval, w0.w, a3);
    a4 = fmaf(oval, w1.x, a4); a5 = fmaf(oval, w1.y, a5);
    a6 = fmaf(oval, w1.z, a6); a7 = fmaf(oval, w1.w, a7);
    a8 = fmaf(oval, w2.x, a8); a9 = fmaf(oval, w2.y, a9);
    a10 = fmaf(oval, w2.z, a10); a11 = fmaf(oval, w2.w, a11);
  }
  const size_t ob2 = ((size_t)b * TD + ts) * N + n0 + nl;
  out[ob2 + 0 * N] = a0 + ob[ts + 0];
  out[ob2 + 1 * N] = a1 + ob[ts + 1];
  out[ob2 + 2 * N] = a2 + ob[ts + 2];
  out[ob2 + 3 * N] = a3 + ob[ts + 3];
  out[ob2 + 4 * N] = a4 + ob[ts + 4];
  out[ob2 + 5 * N] = a5 + ob[ts + 5];
  out[ob2 + 6 * N] = a6 + ob[ts + 6];
  out[ob2 + 7 * N] = a7 + ob[ts + 7];
  out[ob2 + 8 * N] = a8 + ob[ts + 8];
  out[ob2 + 9 * N] = a9 + ob[ts + 9];
  out[ob2 + 10 * N] = a10 + ob[ts + 10];
  out[ob2 + 11 * N] = a11 + ob[ts + 11];
}

extern "C" void kernel_launch(void* const* d_in, const int* in_sizes, int n_in,
                              void* d_out, int out_size, void* d_ws, size_t ws_size,
                              hipStream_t stream) {
  const int B = 2;
  const int Cs[3] = {64, 128, 192};
  const int Hs[3] = {64, 32, 16};
  const size_t out_off[3] = {0,
                             (size_t)2 * TD * 64 * 64,
                             (size_t)2 * TD * 64 * 64 + (size_t)2 * TD * 32 * 32};

  float* ws = (float*)d_ws;
  float* pe = ws;                                 // 3.1 MB
  float* Q = pe + (size_t)4096 * TD;              // each 6.3 MB
  float* Kt = Q + (size_t)B * 4096 * TD;
  float* V = Kt + (size_t)B * 4096 * TD;
  float* Obuf = V + (size_t)B * 4096 * TD;
  // lvl0 candidates for 4 (b,h) at a time: 4*4096 queries x 256 cand
  unsigned* ckey = (unsigned*)(Obuf + (size_t)B * 4096 * TD);            // 16.8 MB
  unsigned short* cidx = (unsigned short*)(ckey + (size_t)4 * 4096 * 256);  // 8.4 MB
  // total ws ~53.5 MB

  for (int lvl = 0; lvl < 3; ++lvl) {
    int C = Cs[lvl], H = Hs[lvl], W = H, N = H * W;
    const float* feat1 = (const float*)d_in[lvl * 2 + 0];
    const float* feat2 = (const float*)d_in[lvl * 2 + 1];
    const float* qw = (const float*)d_in[6 + lvl * 8 + 0];
    const float* qb = (const float*)d_in[6 + lvl * 8 + 1];
    const float* kw = (const float*)d_in[6 + lvl * 8 + 2];
    const float* kb = (const float*)d_in[6 + lvl * 8 + 3];
    const float* vw = (const float*)d_in[6 + lvl * 8 + 4];
    const float* vb = (const float*)d_in[6 + lvl * 8 + 5];
    const float* ow = (const float*)d_in[6 + lvl * 8 + 6];
    const float* ob = (const float*)d_in[6 + lvl * 8 + 7];

    pe_kernel<<<N, TD, 0, stream>>>(pe, W);
    dim3 gq(B * N / 64, 3);
    qkv_tiled<<<gq, 256, 0, stream>>>(feat1, feat2, qw, qb, kw, kb, vw, vb, pe, Q, Kt, V, C, N);

    if (N == 4096) {
      for (int g = 0; g < 2; ++g) {
        // 4 bh x 1024 qg x 2 ranges = 8192 blocks
        attnA_kernel<4096, 2048, false><<<8192, 256, 0, stream>>>(
            Q, Kt, ckey, cidx, V, Obuf, g * 4);
        attnB_kernel<256><<<4 * 4096 / 4, 256, 0, stream>>>(
            ckey, cidx, V, Obuf, 4096, g * 4);
      }
    } else if (N == 1024) {
      attnA_kernel<1024, 1024, true><<<8 * 256, 256, 0, stream>>>(
          Q, Kt, ckey, cidx, V, Obuf, 0);
    } else {
      attnA_kernel<256, 256, true><<<8 * 64, 256, 0, stream>>>(
          Q, Kt, ckey, cidx, V, Obuf, 0);
    }
    oproj_kernel<<<B * (N / OTOK), 256, 0, stream>>>(Obuf, ow, ob, (float*)d_out + out_off[lvl], N);
  }
}

// Round 13
// 1040.022 us; speedup vs baseline: 2.0479x; 2.0479x over previous
//
#include <hip/hip_runtime.h>
#include <math.h>

#define TD 192
#define HD 48
#define KSEL 128
#define QB 4

// Map float to orderable unsigned: a > b (float) <=> f2o(a) > f2o(b)
__device__ __forceinline__ unsigned f2o(float f) {
  unsigned u = __float_as_uint(f);
  return (u & 0x80000000u) ? ~u : (u | 0x80000000u);
}
__device__ __forceinline__ float o2f(unsigned u) {
  unsigned v = (u & 0x80000000u) ? (u & 0x7fffffffu) : ~u;
  return __uint_as_float(v);
}

// 2D sinusoidal positional encoding, matches reference _pos_enc.
__global__ void pe_kernel(float* __restrict__ pe, int W) {
  int n = blockIdx.x;
  int t = threadIdx.x;                      // 0..191
  const float c = -0.09594104554885301f;    // -ln(10000)/96
  float val;
  if (t < 96) {
    float dv = expf((float)t * c);
    val = sinf((float)(n % W) * dv);
  } else {
    float dv = expf((float)(t - 96) * c);
    val = cosf((float)(n / W) * dv);
  }
  pe[n * TD + t] = val;
}

// Tiled QKV projection (r12-proven): 64 tokens x 192 channels per block.
__global__ __launch_bounds__(256) void qkv_tiled(
    const float* __restrict__ feat1, const float* __restrict__ feat2,
    const float* __restrict__ qw, const float* __restrict__ qb,
    const float* __restrict__ kw, const float* __restrict__ kb,
    const float* __restrict__ vw, const float* __restrict__ vb,
    const float* __restrict__ pe,
    float* __restrict__ Q, float* __restrict__ Kt, float* __restrict__ V,
    int C, int N) {
  __shared__ float ftile[64][64];
  const int type = blockIdx.y;
  const int tid = threadIdx.x;
  const int gtok = blockIdx.x * 64;
  const int b = gtok / N, n0 = gtok - b * N;
  const float* feat = (type == 0) ? feat1 : feat2;
  const float* wsel = (type == 0) ? qw : (type == 1) ? kw : vw;
  const float* bsel = (type == 0) ? qb : (type == 1) ? kb : vb;
  const int cg = tid >> 4, tg = tid & 15;
  const int ch0 = cg * 12, t0 = tg * 4;

  float4 z = make_float4(0.f, 0.f, 0.f, 0.f);
  float4 a0 = z, a1 = z, a2 = z, a3 = z, a4 = z, a5 = z,
         a6 = z, a7 = z, a8 = z, a9 = z, a10 = z, a11 = z;

  for (int c0 = 0; c0 < C; c0 += 64) {
#pragma unroll
    for (int rep = 0; rep < 4; ++rep) {
      int off = rep * 1024 + tid * 4;
      int r = off >> 6, cc = off & 63;
      *reinterpret_cast<float4*>(&ftile[r][cc]) =
          *reinterpret_cast<const float4*>(&feat[((size_t)(b * C + c0 + r)) * N + n0 + cc]);
    }
    __syncthreads();
#pragma unroll 8
    for (int k = 0; k < 64; ++k) {
      float4 f4 = *reinterpret_cast<const float4*>(&ftile[k][t0]);
      const float* wr = wsel + (size_t)(c0 + k) * TD + ch0;
      float4 w0 = *reinterpret_cast<const float4*>(wr);
      float4 w1 = *reinterpret_cast<const float4*>(wr + 4);
      float4 w2 = *reinterpret_cast<const float4*>(wr + 8);
#define QFMA(A, WS) A.x = fmaf(WS, f4.x, A.x); A.y = fmaf(WS, f4.y, A.y); \
                    A.z = fmaf(WS, f4.z, A.z); A.w = fmaf(WS, f4.w, A.w);
      QFMA(a0, w0.x) QFMA(a1, w0.y) QFMA(a2, w0.z) QFMA(a3, w0.w)
      QFMA(a4, w1.x) QFMA(a5, w1.y) QFMA(a6, w1.z) QFMA(a7, w1.w)
      QFMA(a8, w2.x) QFMA(a9, w2.y) QFMA(a10, w2.z) QFMA(a11, w2.w)
#undef QFMA
    }
    __syncthreads();
  }
  {
    float4 b0 = *reinterpret_cast<const float4*>(&bsel[ch0]);
    float4 b1 = *reinterpret_cast<const float4*>(&bsel[ch0 + 4]);
    float4 b2 = *reinterpret_cast<const float4*>(&bsel[ch0 + 8]);
#define BADD(A, S) A.x += S; A.y += S; A.z += S; A.w += S;
    BADD(a0, b0.x) BADD(a1, b0.y) BADD(a2, b0.z) BADD(a3, b0.w)
    BADD(a4, b1.x) BADD(a5, b1.y) BADD(a6, b1.z) BADD(a7, b1.w)
    BADD(a8, b2.x) BADD(a9, b2.y) BADD(a10, b2.z) BADD(a11, b2.w)
#undef BADD
  }
  if (type < 2) {
#define PEADD(F, TT) { \
    const float* pr = pe + (size_t)(n0 + t0 + (TT)) * TD + ch0; \
    float4 p0 = *reinterpret_cast<const float4*>(pr); \
    float4 p1 = *reinterpret_cast<const float4*>(pr + 4); \
    float4 p2 = *reinterpret_cast<const float4*>(pr + 8); \
    a0.F += p0.x; a1.F += p0.y; a2.F += p0.z; a3.F += p0.w; \
    a4.F += p1.x; a5.F += p1.y; a6.F += p1.z; a7.F += p1.w; \
    a8.F += p2.x; a9.F += p2.y; a10.F += p2.z; a11.F += p2.w; }
    PEADD(x, 0) PEADD(y, 1) PEADD(z, 2) PEADD(w, 3)
#undef PEADD
  }
  if (type == 1) {
#define KSTORE(A, CI) { int ch = ch0 + (CI); int h = ch / HD, d = ch - h * HD; \
    *reinterpret_cast<float4*>(&Kt[((size_t)(b * 4 + h) * HD + d) * N + n0 + t0]) = A; }
    KSTORE(a0, 0) KSTORE(a1, 1) KSTORE(a2, 2) KSTORE(a3, 3)
    KSTORE(a4, 4) KSTORE(a5, 5) KSTORE(a6, 6) KSTORE(a7, 7)
    KSTORE(a8, 8) KSTORE(a9, 9) KSTORE(a10, 10) KSTORE(a11, 11)
#undef KSTORE
  } else {
    float* out = (type == 0) ? Q : V;
#define RSTORE(F, TT) { \
    float* orow = out + (size_t)(b * N + n0 + t0 + (TT)) * TD + ch0; \
    *reinterpret_cast<float4*>(orow)     = make_float4(a0.F, a1.F, a2.F, a3.F); \
    *reinterpret_cast<float4*>(orow + 4) = make_float4(a4.F, a5.F, a6.F, a7.F); \
    *reinterpret_cast<float4*>(orow + 8) = make_float4(a8.F, a9.F, a10.F, a11.F); }
    RSTORE(x, 0) RSTORE(y, 1) RSTORE(z, 2) RSTORE(w, 3)
#undef RSTORE
  }
}

// ---------------- Stage A ----------------
// r11 structure (RK<=1024, low VGPR, 256-bin radix) + r13 conflict fix:
// pass 1 histograms into the DEAD key-staging LDS region with 4
// conflict-spreading copies per wave (copy = lane&3) -> hot-bin atomic
// serialization drops 64->16 lanes. Region w*1024 is the wave's OWN staging
// area, so no cross-wave hazard and no extra barrier/LDS.
// FUSE (R==1): per-range top-128 == global top-128 -> softmax+gather inline.
template <int N, int RK, bool FUSE>
__global__ __launch_bounds__(256) void attnA_kernel(
    const float* __restrict__ Q, const float* __restrict__ Kt,
    unsigned* __restrict__ ckey, unsigned short* __restrict__ cidx,
    const float* __restrict__ V, float* __restrict__ O, int bh0) {
  constexpr int R = N / RK;
  constexpr int NV4 = RK / 256;           // uint4 regs per lane (<=4)
  constexpr int nq = N / QB;
  constexpr bool SPREAD = (RK == 1024);   // 4-copy pass-1 fits exactly
  __shared__ unsigned sb[QB * RK];        // keys; pass-1 histograms (SPREAD)
  __shared__ float qv[QB][HD];
  __shared__ unsigned hist[4][256];

  const int tid = threadIdx.x;
  const int r = blockIdx.x % R;
  const int qg = (blockIdx.x / R) % nq;
  const int bhloc = blockIdx.x / (R * nq);
  const int bh = bh0 + bhloc;
  const int b = bh >> 2, h = bh & 3;
  const int q0 = qg * QB;
  const float scale = 0.14433756729740643f;  // 1/sqrt(48)

  if (tid < QB * HD) {
    int q = tid / HD, d = tid - q * HD;
    qv[q][d] = Q[((size_t)(b * N + q0 + q)) * TD + h * HD + d];
  }
  __syncthreads();

  const int w = tid >> 6, lane = tid & 63;
  const unsigned long long lanelt = (1ull << lane) - 1ull;
  const float* kt = Kt + ((size_t)(b * 4 + h) * HD) * N + r * RK;

  // ---- score GEMM for this range ----
  for (int j0 = tid * 4; j0 < RK; j0 += 1024) {
    float4 acc[QB];
#pragma unroll
    for (int q = 0; q < QB; ++q) acc[q] = make_float4(0.f, 0.f, 0.f, 0.f);
#pragma unroll
    for (int d4 = 0; d4 < HD; d4 += 4) {
      float4 k0 = *reinterpret_cast<const float4*>(kt + (size_t)(d4 + 0) * N + j0);
      float4 k1 = *reinterpret_cast<const float4*>(kt + (size_t)(d4 + 1) * N + j0);
      float4 k2 = *reinterpret_cast<const float4*>(kt + (size_t)(d4 + 2) * N + j0);
      float4 k3 = *reinterpret_cast<const float4*>(kt + (size_t)(d4 + 3) * N + j0);
#pragma unroll
      for (int q = 0; q < QB; ++q) {
        float4 qq = *reinterpret_cast<const float4*>(&qv[q][d4]);
        acc[q].x = fmaf(qq.x, k0.x, acc[q].x); acc[q].x = fmaf(qq.y, k1.x, acc[q].x);
        acc[q].x = fmaf(qq.z, k2.x, acc[q].x); acc[q].x = fmaf(qq.w, k3.x, acc[q].x);
        acc[q].y = fmaf(qq.x, k0.y, acc[q].y); acc[q].y = fmaf(qq.y, k1.y, acc[q].y);
        acc[q].y = fmaf(qq.z, k2.y, acc[q].y); acc[q].y = fmaf(qq.w, k3.y, acc[q].y);
        acc[q].z = fmaf(qq.x, k0.z, acc[q].z); acc[q].z = fmaf(qq.y, k1.z, acc[q].z);
        acc[q].z = fmaf(qq.z, k2.z, acc[q].z); acc[q].z = fmaf(qq.w, k3.z, acc[q].z);
        acc[q].w = fmaf(qq.x, k0.w, acc[q].w); acc[q].w = fmaf(qq.y, k1.w, acc[q].w);
        acc[q].w = fmaf(qq.z, k2.w, acc[q].w); acc[q].w = fmaf(qq.w, k3.w, acc[q].w);
      }
    }
#pragma unroll
    for (int q = 0; q < QB; ++q) {
      uint4 kk;
      kk.x = f2o(acc[q].x * scale); kk.y = f2o(acc[q].y * scale);
      kk.z = f2o(acc[q].z * scale); kk.w = f2o(acc[q].w * scale);
      *reinterpret_cast<uint4*>(&sb[q * RK + j0]) = kk;
    }
  }
  __syncthreads();

  // ---- per-wave: keys -> registers ----
  uint4 kr[NV4];
#pragma unroll
  for (int i = 0; i < NV4; ++i)
    kr[i] = *reinterpret_cast<const uint4*>(&sb[w * RK + i * 256 + lane * 4]);
  // After this point wave w touches ONLY sb[w*1024 .. w*1024+1024) (its own
  // staging region) -> safe to reuse without a block barrier.

  // ---- radix select: 128th largest within range ----
  unsigned* hw = hist[w];
  unsigned kth = 0u, mask = 0u;
  int rem = KSEL;
#pragma unroll
  for (int shift = 24; shift >= 0; shift -= 8) {
    int v[4], loc = 0;
    if (SPREAD && shift == 24) {
      // pass 1 over ALL keys: 4 copies in the dead staging region
      unsigned* h4 = sb + w * 1024;
#pragma unroll
      for (int i = 0; i < 4; ++i)
        *reinterpret_cast<uint4*>(&h4[i * 256 + lane * 4]) = make_uint4(0, 0, 0, 0);
      const unsigned cbase = (lane & 3u) << 8;
#pragma unroll
      for (int i = 0; i < NV4; ++i) {
        atomicAdd(&h4[cbase + (kr[i].x >> 24)], 1u);
        atomicAdd(&h4[cbase + (kr[i].y >> 24)], 1u);
        atomicAdd(&h4[cbase + (kr[i].z >> 24)], 1u);
        atomicAdd(&h4[cbase + (kr[i].w >> 24)], 1u);
      }
#pragma unroll
      for (int i = 0; i < 4; ++i) {
        int bin = 255 - (lane * 4 + i);
        v[i] = (int)(h4[bin] + h4[bin + 256] + h4[bin + 512] + h4[bin + 768]);
        loc += v[i];
      }
    } else {
#pragma unroll
      for (int i = 0; i < 4; ++i) hw[lane + i * 64] = 0u;
#pragma unroll
      for (int i = 0; i < NV4; ++i) {
        if ((kr[i].x & mask) == kth) atomicAdd(&hw[(kr[i].x >> shift) & 255u], 1u);
        if ((kr[i].y & mask) == kth) atomicAdd(&hw[(kr[i].y >> shift) & 255u], 1u);
        if ((kr[i].z & mask) == kth) atomicAdd(&hw[(kr[i].z >> shift) & 255u], 1u);
        if ((kr[i].w & mask) == kth) atomicAdd(&hw[(kr[i].w >> shift) & 255u], 1u);
      }
#pragma unroll
      for (int i = 0; i < 4; ++i) { v[i] = (int)hw[255 - (lane * 4 + i)]; loc += v[i]; }
    }
    int incl = loc;
#pragma unroll
    for (int off = 1; off < 64; off <<= 1) {
      int t = __shfl_up(incl, off, 64);
      if (lane >= off) incl += t;
    }
    int c = incl - loc;
    int selidx = -1, selexcl = 0;
#pragma unroll
    for (int i = 0; i < 4; ++i) {
      if (selidx < 0 && rem > c && rem <= c + v[i]) {
        selidx = 255 - (lane * 4 + i); selexcl = c;
      }
      c += v[i];
    }
    unsigned long long vote = __ballot(selidx >= 0);
    int src = __ffsll((long long)vote) - 1;
    selidx = __shfl(selidx, src, 64);
    selexcl = __shfl(selexcl, src, 64);
    rem -= selexcl;
    kth |= ((unsigned)selidx << shift);
    mask |= (0xFFu << shift);
  }
  const int need_eq = rem;   // boundary slots among ==kth, lowest index first

  if constexpr (FUSE) {
    unsigned mk = 0u;
#pragma unroll
    for (int i = 0; i < NV4; ++i) {
      unsigned a_ = kr[i].x > kr[i].y ? kr[i].x : kr[i].y;
      unsigned b_ = kr[i].z > kr[i].w ? kr[i].z : kr[i].w;
      a_ = a_ > b_ ? a_ : b_; mk = a_ > mk ? a_ : mk;
    }
    for (int off = 32; off > 0; off >>= 1) {
      unsigned o = (unsigned)__shfl_xor((int)mk, off, 64);
      mk = o > mk ? o : mk;
    }
    const float mx = o2f(mk);

    __shared__ int idxb[4][KSEL];
    __shared__ float wb[4][KSEL];
    int selbase = 0, eqbase = 0;
    float lz = 0.f;
#pragma unroll
    for (int i = 0; i < NV4; ++i) {
      const int jb = i * 256 + lane * 4;
      const unsigned u0 = kr[i].x, u1 = kr[i].y, u2 = kr[i].z, u3 = kr[i].w;
      const bool e0 = (u0 == kth), e1 = (u1 == kth), e2 = (u2 == kth), e3 = (u3 == kth);
      const unsigned long long b0 = __ballot(e0), b1 = __ballot(e1), b2 = __ballot(e2), b3 = __ballot(e3);
      const int eqlt = __popcll(b0 & lanelt) + __popcll(b1 & lanelt) + __popcll(b2 & lanelt) + __popcll(b3 & lanelt);
      int eo = 0;
      const bool s0 = (u0 > kth) || (e0 && (eqbase + eqlt + eo) < need_eq); eo += e0 ? 1 : 0;
      const bool s1 = (u1 > kth) || (e1 && (eqbase + eqlt + eo) < need_eq); eo += e1 ? 1 : 0;
      const bool s2 = (u2 > kth) || (e2 && (eqbase + eqlt + eo) < need_eq); eo += e2 ? 1 : 0;
      const bool s3 = (u3 > kth) || (e3 && (eqbase + eqlt + eo) < need_eq); eo += e3 ? 1 : 0;
      const unsigned long long c0 = __ballot(s0), c1 = __ballot(s1), c2 = __ballot(s2), c3 = __ballot(s3);
      const int sellt = __popcll(c0 & lanelt) + __popcll(c1 & lanelt) + __popcll(c2 & lanelt) + __popcll(c3 & lanelt);
      int so = 0;
      if (s0) { int p = selbase + sellt + so; float e = expf(o2f(u0) - mx); idxb[w][p] = jb + 0; wb[w][p] = e; lz += e; } so += s0 ? 1 : 0;
      if (s1) { int p = selbase + sellt + so; float e = expf(o2f(u1) - mx); idxb[w][p] = jb + 1; wb[w][p] = e; lz += e; } so += s1 ? 1 : 0;
      if (s2) { int p = selbase + sellt + so; float e = expf(o2f(u2) - mx); idxb[w][p] = jb + 2; wb[w][p] = e; lz += e; } so += s2 ? 1 : 0;
      if (s3) { int p = selbase + sellt + so; float e = expf(o2f(u3) - mx); idxb[w][p] = jb + 3; wb[w][p] = e; lz += e; } so += s3 ? 1 : 0;
      eqbase += __popcll(b0) + __popcll(b1) + __popcll(b2) + __popcll(b3);
      selbase += __popcll(c0) + __popcll(c1) + __popcll(c2) + __popcll(c3);
    }
    for (int off = 32; off > 0; off >>= 1) lz += __shfl_xor(lz, off, 64);
    const float rz = 1.f / lz;
    if (lane < HD) {
      float acc = 0.f;
#pragma unroll 4
      for (int p = 0; p < KSEL; ++p) {
        acc = fmaf(wb[w][p], V[((size_t)(b * N + idxb[w][p])) * TD + h * HD + lane], acc);
      }
      O[((size_t)(b * N + q0 + w)) * TD + h * HD + lane] = acc * rz;
    }
  } else {
    unsigned* ok = ckey + (((size_t)bhloc * N + q0 + w) * R + r) * KSEL;
    unsigned short* oi = cidx + (((size_t)bhloc * N + q0 + w) * R + r) * KSEL;
    int selbase = 0, eqbase = 0;
#pragma unroll
    for (int i = 0; i < NV4; ++i) {
      const int jb = r * RK + i * 256 + lane * 4;
      const unsigned u0 = kr[i].x, u1 = kr[i].y, u2 = kr[i].z, u3 = kr[i].w;
      const bool e0 = (u0 == kth), e1 = (u1 == kth), e2 = (u2 == kth), e3 = (u3 == kth);
      const unsigned long long b0 = __ballot(e0), b1 = __ballot(e1), b2 = __ballot(e2), b3 = __ballot(e3);
      const int eqlt = __popcll(b0 & lanelt) + __popcll(b1 & lanelt) + __popcll(b2 & lanelt) + __popcll(b3 & lanelt);
      int eo = 0;
      const bool s0 = (u0 > kth) || (e0 && (eqbase + eqlt + eo) < need_eq); eo += e0 ? 1 : 0;
      const bool s1 = (u1 > kth) || (e1 && (eqbase + eqlt + eo) < need_eq); eo += e1 ? 1 : 0;
      const bool s2 = (u2 > kth) || (e2 && (eqbase + eqlt + eo) < need_eq); eo += e2 ? 1 : 0;
      const bool s3 = (u3 > kth) || (e3 && (eqbase + eqlt + eo) < need_eq); eo += e3 ? 1 : 0;
      const unsigned long long c0 = __ballot(s0), c1 = __ballot(s1), c2 = __ballot(s2), c3 = __ballot(s3);
      const int sellt = __popcll(c0 & lanelt) + __popcll(c1 & lanelt) + __popcll(c2 & lanelt) + __popcll(c3 & lanelt);
      int so = 0;
      if (s0) { int p = selbase + sellt + so; ok[p] = u0; oi[p] = (unsigned short)(jb + 0); } so += s0 ? 1 : 0;
      if (s1) { int p = selbase + sellt + so; ok[p] = u1; oi[p] = (unsigned short)(jb + 1); } so += s1 ? 1 : 0;
      if (s2) { int p = selbase + sellt + so; ok[p] = u2; oi[p] = (unsigned short)(jb + 2); } so += s2 ? 1 : 0;
      if (s3) { int p = selbase + sellt + so; ok[p] = u3; oi[p] = (unsigned short)(jb + 3); } so += s3 ? 1 : 0;
      eqbase += __popcll(b0) + __popcll(b1) + __popcll(b2) + __popcll(b3);
      selbase += __popcll(c0) + __popcll(c1) + __popcll(c2) + __popcll(c3);
    }
  }
}

// ---------------- Stage B ----------------
template <int CN>
__global__ __launch_bounds__(256) void attnB_kernel(
    const unsigned* __restrict__ ckey, const unsigned short* __restrict__ cidx,
    const float* __restrict__ V, float* __restrict__ O, int N, int bh0) {
  constexpr int CL = CN / 64;
  __shared__ unsigned hist[4][256];
  __shared__ int idxb[4][KSEL];
  __shared__ float wb[4][KSEL];

  const int tid = threadIdx.x, w = tid >> 6, lane = tid & 63;
  const unsigned long long lanelt = (1ull << lane) - 1ull;
  const int g = blockIdx.x * 4 + w;
  const int bhloc = g / N;
  const int qi = g - bhloc * N;
  const int bh = bh0 + bhloc;
  const int b = bh >> 2, h = bh & 3;

  unsigned ck[CL], ci[CL];
#pragma unroll
  for (int i = 0; i < CL; ++i) {
    ck[i] = ckey[(size_t)g * CN + i * 64 + lane];
    ci[i] = cidx[(size_t)g * CN + i * 64 + lane];
  }

  unsigned mk = 0u;
#pragma unroll
  for (int i = 0; i < CL; ++i) mk = ck[i] > mk ? ck[i] : mk;
  for (int off = 32; off > 0; off >>= 1) {
    unsigned o = (unsigned)__shfl_xor((int)mk, off, 64);
    mk = o > mk ? o : mk;
  }
  const float mx = o2f(mk);

  unsigned* hw = hist[w];
  unsigned kth = 0u, mask = 0u;
  int rem = KSEL;
#pragma unroll
  for (int shift = 24; shift >= 0; shift -= 8) {
#pragma unroll
    for (int i = 0; i < 4; ++i) hw[lane + i * 64] = 0u;
#pragma unroll
    for (int i = 0; i < CL; ++i)
      if ((ck[i] & mask) == kth) atomicAdd(&hw[(ck[i] >> shift) & 255u], 1u);
    int v[4], loc = 0;
#pragma unroll
    for (int i = 0; i < 4; ++i) { v[i] = (int)hw[255 - (lane * 4 + i)]; loc += v[i]; }
    int incl = loc;
#pragma unroll
    for (int off = 1; off < 64; off <<= 1) {
      int t = __shfl_up(incl, off, 64);
      if (lane >= off) incl += t;
    }
    int c = incl - loc;
    int selidx = -1, selexcl = 0;
#pragma unroll
    for (int i = 0; i < 4; ++i) {
      if (selidx < 0 && rem > c && rem <= c + v[i]) {
        selidx = 255 - (lane * 4 + i); selexcl = c;
      }
      c += v[i];
    }
    unsigned long long vote = __ballot(selidx >= 0);
    int src = __ffsll((long long)vote) - 1;
    selidx = __shfl(selidx, src, 64);
    selexcl = __shfl(selexcl, src, 64);
    rem -= selexcl;
    kth |= ((unsigned)selidx << shift);
    mask |= (0xFFu << shift);
  }
  const int need_eq = rem;

  int selbase = 0, eqbase = 0;
  float lz = 0.f;
#pragma unroll
  for (int i = 0; i < CL; ++i) {
    const unsigned u = ck[i];
    const bool eq = (u == kth);
    const unsigned long long beq = __ballot(eq);
    const int eqrank = eqbase + __popcll(beq & lanelt);
    const bool sel = (u > kth) || (eq && eqrank < need_eq);
    const unsigned long long bsel = __ballot(sel);
    const int pos = selbase + __popcll(bsel & lanelt);
    if (sel) {
      float e = expf(o2f(u) - mx);
      idxb[w][pos] = (int)ci[i];
      wb[w][pos] = e;
      lz += e;
    }
    eqbase += __popcll(beq);
    selbase += __popcll(bsel);
  }
  for (int off = 32; off > 0; off >>= 1) lz += __shfl_xor(lz, off, 64);
  const float rz = 1.f / lz;

  if (lane < HD) {
    float acc = 0.f;
#pragma unroll 4
    for (int p = 0; p < KSEL; ++p) {
      acc = fmaf(wb[w][p], V[((size_t)(b * N + idxb[w][p])) * TD + h * HD + lane], acc);
    }
    O[((size_t)(b * N + qi)) * TD + h * HD + lane] = acc * rz;
  }
}

// out[b, t, n] = O[b, n, :] . ow[:, t] + ob[t]; 16-token tile (r11-proven).
#define OTOK 16
__global__ __launch_bounds__(256) void oproj_kernel(
    const float* __restrict__ O, const float* __restrict__ ow,
    const float* __restrict__ ob, float* __restrict__ out, int N) {
  __shared__ float otile[OTOK][TD + 1];
  const int tid = threadIdx.x;
  const int nt = N / OTOK;
  const int b = blockIdx.x / nt;
  const int n0 = (blockIdx.x % nt) * OTOK;
  const float* obase = O + ((size_t)(b * N + n0)) * TD;
  for (int idx = tid * 4; idx < OTOK * TD; idx += 1024) {
    float4 v = *reinterpret_cast<const float4*>(obase + idx);
    int r = idx / TD, c = idx - r * TD;
    otile[r][c] = v.x; otile[r][c + 1] = v.y; otile[r][c + 2] = v.z; otile[r][c + 3] = v.w;
  }
  __syncthreads();
  const int nl = tid & 15;
  const int ts = (tid >> 4) * 12;
  float a0 = 0.f, a1 = 0.f, a2 = 0.f, a3 = 0.f, a4 = 0.f, a5 = 0.f,
        a6 = 0.f, a7 = 0.f, a8 = 0.f, a9 = 0.f, a10 = 0.f, a11 = 0.f;
  for (int c = 0; c < TD; ++c) {
    float oval = otile[nl][c];
    const float* wr = ow + c * TD + ts;
    float4 w0 = *reinterpret_cast<const float4*>(wr);
    float4 w1 = *reinterpret_cast<const float4*>(wr + 4);
    float4 w2 = *reinterpret_cast<const float4*>(wr + 8);
    a0 = fmaf(oval, w0.x, a0); a1 = fmaf(oval, w0.y, a1);
    a2 = fmaf(oval, w0.z, a2); a3 = fmaf(oval, w0.w, a3);
    a4 = fmaf(oval, w1.x, a4); a5 = fmaf(oval, w1.y, a5);
    a6 = fmaf(oval, w1.z, a6); a7 = fmaf(oval, w1.w, a7);
    a8 = fmaf(oval, w2.x, a8); a9 = fmaf(oval, w2.y, a9);
    a10 = fmaf(oval, w2.z, a10); a11 = fmaf(oval, w2.w, a11);
  }
  const size_t ob2 = ((size_t)b * TD + ts) * N + n0 + nl;
  out[ob2 + 0 * N] = a0 + ob[ts + 0];
  out[ob2 + 1 * N] = a1 + ob[ts + 1];
  out[ob2 + 2 * N] = a2 + ob[ts + 2];
  out[ob2 + 3 * N] = a3 + ob[ts + 3];
  out[ob2 + 4 * N] = a4 + ob[ts + 4];
  out[ob2 + 5 * N] = a5 + ob[ts + 5];
  out[ob2 + 6 * N] = a6 + ob[ts + 6];
  out[ob2 + 7 * N] = a7 + ob[ts + 7];
  out[ob2 + 8 * N] = a8 + ob[ts + 8];
  out[ob2 + 9 * N] = a9 + ob[ts + 9];
  out[ob2 + 10 * N] = a10 + ob[ts + 10];
  out[ob2 + 11 * N] = a11 + ob[ts + 11];
}

extern "C" void kernel_launch(void* const* d_in, const int* in_sizes, int n_in,
                              void* d_out, int out_size, void* d_ws, size_t ws_size,
                              hipStream_t stream) {
  const int B = 2;
  const int Cs[3] = {64, 128, 192};
  const int Hs[3] = {64, 32, 16};
  const size_t out_off[3] = {0,
                             (size_t)2 * TD * 64 * 64,
                             (size_t)2 * TD * 64 * 64 + (size_t)2 * TD * 32 * 32};

  float* ws = (float*)d_ws;
  float* pe = ws;                                 // 3.1 MB
  float* Q = pe + (size_t)4096 * TD;              // each 6.3 MB
  float* Kt = Q + (size_t)B * 4096 * TD;
  float* V = Kt + (size_t)B * 4096 * TD;
  float* Obuf = V + (size_t)B * 4096 * TD;
  // lvl0 candidates for 2 (b,h) at a time: 2*4096 queries x 512 cand
  unsigned* ckey = (unsigned*)(Obuf + (size_t)B * 4096 * TD);               // 16.8 MB
  unsigned short* cidx = (unsigned short*)(ckey + (size_t)2 * 4096 * 512);  // 8.4 MB
  // total ws ~53.5 MB (r12-proven)

  for (int lvl = 0; lvl < 3; ++lvl) {
    int C = Cs[lvl], H = Hs[lvl], W = H, N = H * W;
    const float* feat1 = (const float*)d_in[lvl * 2 + 0];
    const float* feat2 = (const float*)d_in[lvl * 2 + 1];
    const float* qw = (const float*)d_in[6 + lvl * 8 + 0];
    const float* qb = (const float*)d_in[6 + lvl * 8 + 1];
    const float* kw = (const float*)d_in[6 + lvl * 8 + 2];
    const float* kb = (const float*)d_in[6 + lvl * 8 + 3];
    const float* vw = (const float*)d_in[6 + lvl * 8 + 4];
    const float* vb = (const float*)d_in[6 + lvl * 8 + 5];
    const float* ow = (const float*)d_in[6 + lvl * 8 + 6];
    const float* ob = (const float*)d_in[6 + lvl * 8 + 7];

    pe_kernel<<<N, TD, 0, stream>>>(pe, W);
    dim3 gq(B * N / 64, 3);
    qkv_tiled<<<gq, 256, 0, stream>>>(feat1, feat2, qw, qb, kw, kb, vw, vb, pe, Q, Kt, V, C, N);

    if (N == 4096) {
      for (int g = 0; g < 4; ++g) {
        // 2 bh x 1024 qg x 4 ranges = 8192 blocks
        attnA_kernel<4096, 1024, false><<<8192, 256, 0, stream>>>(
            Q, Kt, ckey, cidx, V, Obuf, g * 2);
        attnB_kernel<512><<<2 * 4096 / 4, 256, 0, stream>>>(
            ckey, cidx, V, Obuf, 4096, g * 2);
      }
    } else if (N == 1024) {
      attnA_kernel<1024, 1024, true><<<8 * 256, 256, 0, stream>>>(
          Q, Kt, ckey, cidx, V, Obuf, 0);
    } else {
      attnA_kernel<256, 256, true><<<8 * 64, 256, 0, stream>>>(
          Q, Kt, ckey, cidx, V, Obuf, 0);
    }
    oproj_kernel<<<B * (N / OTOK), 256, 0, stream>>>(Obuf, ow, ob, (float*)d_out + out_off[lvl], N);
  }
}

// Round 14
// 970.970 us; speedup vs baseline: 2.1936x; 1.0711x over previous
//
#include <hip/hip_runtime.h>
#include <math.h>

#define TD 192
#define HD 48
#define KSEL 128
#define QB 4

// Map float to orderable unsigned: a > b (float) <=> f2o(a) > f2o(b)
__device__ __forceinline__ unsigned f2o(float f) {
  unsigned u = __float_as_uint(f);
  return (u & 0x80000000u) ? ~u : (u | 0x80000000u);
}
__device__ __forceinline__ float o2f(unsigned u) {
  unsigned v = (u & 0x80000000u) ? (u & 0x7fffffffu) : ~u;
  return __uint_as_float(v);
}

// 2D sinusoidal positional encoding, matches reference _pos_enc.
__global__ void pe_kernel(float* __restrict__ pe, int W) {
  int n = blockIdx.x;
  int t = threadIdx.x;                      // 0..191
  const float c = -0.09594104554885301f;    // -ln(10000)/96
  float val;
  if (t < 96) {
    float dv = expf((float)t * c);
    val = sinf((float)(n % W) * dv);
  } else {
    float dv = expf((float)(t - 96) * c);
    val = cosf((float)(n / W) * dv);
  }
  pe[n * TD + t] = val;
}

// Tiled QKV projection (r12-proven): 64 tokens x 192 channels per block.
__global__ __launch_bounds__(256) void qkv_tiled(
    const float* __restrict__ feat1, const float* __restrict__ feat2,
    const float* __restrict__ qw, const float* __restrict__ qb,
    const float* __restrict__ kw, const float* __restrict__ kb,
    const float* __restrict__ vw, const float* __restrict__ vb,
    const float* __restrict__ pe,
    float* __restrict__ Q, float* __restrict__ Kt, float* __restrict__ V,
    int C, int N) {
  __shared__ float ftile[64][64];
  const int type = blockIdx.y;
  const int tid = threadIdx.x;
  const int gtok = blockIdx.x * 64;
  const int b = gtok / N, n0 = gtok - b * N;
  const float* feat = (type == 0) ? feat1 : feat2;
  const float* wsel = (type == 0) ? qw : (type == 1) ? kw : vw;
  const float* bsel = (type == 0) ? qb : (type == 1) ? kb : vb;
  const int cg = tid >> 4, tg = tid & 15;
  const int ch0 = cg * 12, t0 = tg * 4;

  float4 z = make_float4(0.f, 0.f, 0.f, 0.f);
  float4 a0 = z, a1 = z, a2 = z, a3 = z, a4 = z, a5 = z,
         a6 = z, a7 = z, a8 = z, a9 = z, a10 = z, a11 = z;

  for (int c0 = 0; c0 < C; c0 += 64) {
#pragma unroll
    for (int rep = 0; rep < 4; ++rep) {
      int off = rep * 1024 + tid * 4;
      int r = off >> 6, cc = off & 63;
      *reinterpret_cast<float4*>(&ftile[r][cc]) =
          *reinterpret_cast<const float4*>(&feat[((size_t)(b * C + c0 + r)) * N + n0 + cc]);
    }
    __syncthreads();
#pragma unroll 8
    for (int k = 0; k < 64; ++k) {
      float4 f4 = *reinterpret_cast<const float4*>(&ftile[k][t0]);
      const float* wr = wsel + (size_t)(c0 + k) * TD + ch0;
      float4 w0 = *reinterpret_cast<const float4*>(wr);
      float4 w1 = *reinterpret_cast<const float4*>(wr + 4);
      float4 w2 = *reinterpret_cast<const float4*>(wr + 8);
#define QFMA(A, WS) A.x = fmaf(WS, f4.x, A.x); A.y = fmaf(WS, f4.y, A.y); \
                    A.z = fmaf(WS, f4.z, A.z); A.w = fmaf(WS, f4.w, A.w);
      QFMA(a0, w0.x) QFMA(a1, w0.y) QFMA(a2, w0.z) QFMA(a3, w0.w)
      QFMA(a4, w1.x) QFMA(a5, w1.y) QFMA(a6, w1.z) QFMA(a7, w1.w)
      QFMA(a8, w2.x) QFMA(a9, w2.y) QFMA(a10, w2.z) QFMA(a11, w2.w)
#undef QFMA
    }
    __syncthreads();
  }
  {
    float4 b0 = *reinterpret_cast<const float4*>(&bsel[ch0]);
    float4 b1 = *reinterpret_cast<const float4*>(&bsel[ch0 + 4]);
    float4 b2 = *reinterpret_cast<const float4*>(&bsel[ch0 + 8]);
#define BADD(A, S) A.x += S; A.y += S; A.z += S; A.w += S;
    BADD(a0, b0.x) BADD(a1, b0.y) BADD(a2, b0.z) BADD(a3, b0.w)
    BADD(a4, b1.x) BADD(a5, b1.y) BADD(a6, b1.z) BADD(a7, b1.w)
    BADD(a8, b2.x) BADD(a9, b2.y) BADD(a10, b2.z) BADD(a11, b2.w)
#undef BADD
  }
  if (type < 2) {
#define PEADD(F, TT) { \
    const float* pr = pe + (size_t)(n0 + t0 + (TT)) * TD + ch0; \
    float4 p0 = *reinterpret_cast<const float4*>(pr); \
    float4 p1 = *reinterpret_cast<const float4*>(pr + 4); \
    float4 p2 = *reinterpret_cast<const float4*>(pr + 8); \
    a0.F += p0.x; a1.F += p0.y; a2.F += p0.z; a3.F += p0.w; \
    a4.F += p1.x; a5.F += p1.y; a6.F += p1.z; a7.F += p1.w; \
    a8.F += p2.x; a9.F += p2.y; a10.F += p2.z; a11.F += p2.w; }
    PEADD(x, 0) PEADD(y, 1) PEADD(z, 2) PEADD(w, 3)
#undef PEADD
  }
  if (type == 1) {
#define KSTORE(A, CI) { int ch = ch0 + (CI); int h = ch / HD, d = ch - h * HD; \
    *reinterpret_cast<float4*>(&Kt[((size_t)(b * 4 + h) * HD + d) * N + n0 + t0]) = A; }
    KSTORE(a0, 0) KSTORE(a1, 1) KSTORE(a2, 2) KSTORE(a3, 3)
    KSTORE(a4, 4) KSTORE(a5, 5) KSTORE(a6, 6) KSTORE(a7, 7)
    KSTORE(a8, 8) KSTORE(a9, 9) KSTORE(a10, 10) KSTORE(a11, 11)
#undef KSTORE
  } else {
    float* out = (type == 0) ? Q : V;
#define RSTORE(F, TT) { \
    float* orow = out + (size_t)(b * N + n0 + t0 + (TT)) * TD + ch0; \
    *reinterpret_cast<float4*>(orow)     = make_float4(a0.F, a1.F, a2.F, a3.F); \
    *reinterpret_cast<float4*>(orow + 4) = make_float4(a4.F, a5.F, a6.F, a7.F); \
    *reinterpret_cast<float4*>(orow + 8) = make_float4(a8.F, a9.F, a10.F, a11.F); }
    RSTORE(x, 0) RSTORE(y, 1) RSTORE(z, 2) RSTORE(w, 3)
#undef RSTORE
  }
}

// ---------------- Stage A ----------------
// r13 structure + r14 fix: ALL radix passes histogram into the dead key-
// staging region with NCOPY copies per wave, each copy XOR-BANK-ROTATED
// (copy c stores bin b at c*256 + (b ^ (c<<3))). r13 lesson: copies at
// c*256 + b put all copies of bin b in the SAME bank (256%32==0) -> zero
// conflict reduction. XOR rotation puts them in banks b%32 ^ {0,8,16,24}.
// FUSE (R==1): per-range top-128 == global top-128 -> softmax+gather inline.
template <int N, int RK, bool FUSE>
__global__ __launch_bounds__(256) void attnA_kernel(
    const float* __restrict__ Q, const float* __restrict__ Kt,
    unsigned* __restrict__ ckey, unsigned short* __restrict__ cidx,
    const float* __restrict__ V, float* __restrict__ O, int bh0) {
  constexpr int R = N / RK;
  constexpr int NV4 = RK / 256;           // uint4 regs per lane (<=4)
  constexpr int nq = N / QB;
  constexpr int NCOPY = RK / 256;         // histogram copies per wave (1 or 4)
  __shared__ unsigned sb[QB * RK];        // keys; then per-wave histograms
  __shared__ float qv[QB][HD];

  const int tid = threadIdx.x;
  const int r = blockIdx.x % R;
  const int qg = (blockIdx.x / R) % nq;
  const int bhloc = blockIdx.x / (R * nq);
  const int bh = bh0 + bhloc;
  const int b = bh >> 2, h = bh & 3;
  const int q0 = qg * QB;
  const float scale = 0.14433756729740643f;  // 1/sqrt(48)

  if (tid < QB * HD) {
    int q = tid / HD, d = tid - q * HD;
    qv[q][d] = Q[((size_t)(b * N + q0 + q)) * TD + h * HD + d];
  }
  __syncthreads();

  const int w = tid >> 6, lane = tid & 63;
  const unsigned long long lanelt = (1ull << lane) - 1ull;
  const float* kt = Kt + ((size_t)(b * 4 + h) * HD) * N + r * RK;

  // ---- score GEMM for this range ----
  for (int j0 = tid * 4; j0 < RK; j0 += 1024) {
    float4 acc[QB];
#pragma unroll
    for (int q = 0; q < QB; ++q) acc[q] = make_float4(0.f, 0.f, 0.f, 0.f);
#pragma unroll
    for (int d4 = 0; d4 < HD; d4 += 4) {
      float4 k0 = *reinterpret_cast<const float4*>(kt + (size_t)(d4 + 0) * N + j0);
      float4 k1 = *reinterpret_cast<const float4*>(kt + (size_t)(d4 + 1) * N + j0);
      float4 k2 = *reinterpret_cast<const float4*>(kt + (size_t)(d4 + 2) * N + j0);
      float4 k3 = *reinterpret_cast<const float4*>(kt + (size_t)(d4 + 3) * N + j0);
#pragma unroll
      for (int q = 0; q < QB; ++q) {
        float4 qq = *reinterpret_cast<const float4*>(&qv[q][d4]);
        acc[q].x = fmaf(qq.x, k0.x, acc[q].x); acc[q].x = fmaf(qq.y, k1.x, acc[q].x);
        acc[q].x = fmaf(qq.z, k2.x, acc[q].x); acc[q].x = fmaf(qq.w, k3.x, acc[q].x);
        acc[q].y = fmaf(qq.x, k0.y, acc[q].y); acc[q].y = fmaf(qq.y, k1.y, acc[q].y);
        acc[q].y = fmaf(qq.z, k2.y, acc[q].y); acc[q].y = fmaf(qq.w, k3.y, acc[q].y);
        acc[q].z = fmaf(qq.x, k0.z, acc[q].z); acc[q].z = fmaf(qq.y, k1.z, acc[q].z);
        acc[q].z = fmaf(qq.z, k2.z, acc[q].z); acc[q].z = fmaf(qq.w, k3.z, acc[q].z);
        acc[q].w = fmaf(qq.x, k0.w, acc[q].w); acc[q].w = fmaf(qq.y, k1.w, acc[q].w);
        acc[q].w = fmaf(qq.z, k2.w, acc[q].w); acc[q].w = fmaf(qq.w, k3.w, acc[q].w);
      }
    }
#pragma unroll
    for (int q = 0; q < QB; ++q) {
      uint4 kk;
      kk.x = f2o(acc[q].x * scale); kk.y = f2o(acc[q].y * scale);
      kk.z = f2o(acc[q].z * scale); kk.w = f2o(acc[q].w * scale);
      *reinterpret_cast<uint4*>(&sb[q * RK + j0]) = kk;
    }
  }
  __syncthreads();

  // ---- per-wave: keys -> registers ----
  uint4 kr[NV4];
#pragma unroll
  for (int i = 0; i < NV4; ++i)
    kr[i] = *reinterpret_cast<const uint4*>(&sb[w * RK + i * 256 + lane * 4]);
  // After this point wave w touches ONLY sb[w*RK .. w*RK+RK) (its own
  // staging region) -> safe to reuse as histograms without a block barrier.

  unsigned* h4 = sb + w * RK;                 // NCOPY copies of 256 bins
  const unsigned cb = ((unsigned)lane & (NCOPY - 1u)) << 8;   // copy base
  const unsigned cx = ((unsigned)lane & (NCOPY - 1u)) << 3;   // bank-rotate XOR

  // ---- radix select: 128th largest within range ----
  unsigned kth = 0u, mask = 0u;
  int rem = KSEL;
#pragma unroll
  for (int shift = 24; shift >= 0; shift -= 8) {
    // zero this wave's histogram region
#pragma unroll
    for (int i = 0; i < NCOPY; ++i)
      *reinterpret_cast<uint4*>(&h4[i * 256 + lane * 4]) = make_uint4(0, 0, 0, 0);
    if (shift == 24) {
#pragma unroll
      for (int i = 0; i < NV4; ++i) {
        atomicAdd(&h4[cb + (((kr[i].x >> 24)) ^ cx)], 1u);
        atomicAdd(&h4[cb + (((kr[i].y >> 24)) ^ cx)], 1u);
        atomicAdd(&h4[cb + (((kr[i].z >> 24)) ^ cx)], 1u);
        atomicAdd(&h4[cb + (((kr[i].w >> 24)) ^ cx)], 1u);
      }
    } else {
#pragma unroll
      for (int i = 0; i < NV4; ++i) {
        if ((kr[i].x & mask) == kth) atomicAdd(&h4[cb + (((kr[i].x >> shift) & 255u) ^ cx)], 1u);
        if ((kr[i].y & mask) == kth) atomicAdd(&h4[cb + (((kr[i].y >> shift) & 255u) ^ cx)], 1u);
        if ((kr[i].z & mask) == kth) atomicAdd(&h4[cb + (((kr[i].z >> shift) & 255u) ^ cx)], 1u);
        if ((kr[i].w & mask) == kth) atomicAdd(&h4[cb + (((kr[i].w >> shift) & 255u) ^ cx)], 1u);
      }
    }
    int v[4], loc = 0;
#pragma unroll
    for (int i = 0; i < 4; ++i) {
      unsigned bin = (unsigned)(255 - (lane * 4 + i));
      unsigned s = 0;
#pragma unroll
      for (int c = 0; c < NCOPY; ++c) s += h4[c * 256 + (bin ^ ((unsigned)c << 3))];
      v[i] = (int)s;
      loc += v[i];
    }
    int incl = loc;
#pragma unroll
    for (int off = 1; off < 64; off <<= 1) {
      int t = __shfl_up(incl, off, 64);
      if (lane >= off) incl += t;
    }
    int c = incl - loc;
    int selidx = -1, selexcl = 0;
#pragma unroll
    for (int i = 0; i < 4; ++i) {
      if (selidx < 0 && rem > c && rem <= c + v[i]) {
        selidx = 255 - (lane * 4 + i); selexcl = c;
      }
      c += v[i];
    }
    unsigned long long vote = __ballot(selidx >= 0);
    int src = __ffsll((long long)vote) - 1;
    selidx = __shfl(selidx, src, 64);
    selexcl = __shfl(selexcl, src, 64);
    rem -= selexcl;
    kth |= ((unsigned)selidx << shift);
    mask |= (0xFFu << shift);
  }
  const int need_eq = rem;   // boundary slots among ==kth, lowest index first

  if constexpr (FUSE) {
    unsigned mk = 0u;
#pragma unroll
    for (int i = 0; i < NV4; ++i) {
      unsigned a_ = kr[i].x > kr[i].y ? kr[i].x : kr[i].y;
      unsigned b_ = kr[i].z > kr[i].w ? kr[i].z : kr[i].w;
      a_ = a_ > b_ ? a_ : b_; mk = a_ > mk ? a_ : mk;
    }
    for (int off = 32; off > 0; off >>= 1) {
      unsigned o = (unsigned)__shfl_xor((int)mk, off, 64);
      mk = o > mk ? o : mk;
    }
    const float mx = o2f(mk);

    __shared__ int idxb[4][KSEL];
    __shared__ float wb[4][KSEL];
    int selbase = 0, eqbase = 0;
    float lz = 0.f;
#pragma unroll
    for (int i = 0; i < NV4; ++i) {
      const int jb = i * 256 + lane * 4;
      const unsigned u0 = kr[i].x, u1 = kr[i].y, u2 = kr[i].z, u3 = kr[i].w;
      const bool e0 = (u0 == kth), e1 = (u1 == kth), e2 = (u2 == kth), e3 = (u3 == kth);
      const unsigned long long b0 = __ballot(e0), b1 = __ballot(e1), b2 = __ballot(e2), b3 = __ballot(e3);
      const int eqlt = __popcll(b0 & lanelt) + __popcll(b1 & lanelt) + __popcll(b2 & lanelt) + __popcll(b3 & lanelt);
      int eo = 0;
      const bool s0 = (u0 > kth) || (e0 && (eqbase + eqlt + eo) < need_eq); eo += e0 ? 1 : 0;
      const bool s1 = (u1 > kth) || (e1 && (eqbase + eqlt + eo) < need_eq); eo += e1 ? 1 : 0;
      const bool s2 = (u2 > kth) || (e2 && (eqbase + eqlt + eo) < need_eq); eo += e2 ? 1 : 0;
      const bool s3 = (u3 > kth) || (e3 && (eqbase + eqlt + eo) < need_eq); eo += e3 ? 1 : 0;
      const unsigned long long c0 = __ballot(s0), c1 = __ballot(s1), c2 = __ballot(s2), c3 = __ballot(s3);
      const int sellt = __popcll(c0 & lanelt) + __popcll(c1 & lanelt) + __popcll(c2 & lanelt) + __popcll(c3 & lanelt);
      int so = 0;
      if (s0) { int p = selbase + sellt + so; float e = expf(o2f(u0) - mx); idxb[w][p] = jb + 0; wb[w][p] = e; lz += e; } so += s0 ? 1 : 0;
      if (s1) { int p = selbase + sellt + so; float e = expf(o2f(u1) - mx); idxb[w][p] = jb + 1; wb[w][p] = e; lz += e; } so += s1 ? 1 : 0;
      if (s2) { int p = selbase + sellt + so; float e = expf(o2f(u2) - mx); idxb[w][p] = jb + 2; wb[w][p] = e; lz += e; } so += s2 ? 1 : 0;
      if (s3) { int p = selbase + sellt + so; float e = expf(o2f(u3) - mx); idxb[w][p] = jb + 3; wb[w][p] = e; lz += e; } so += s3 ? 1 : 0;
      eqbase += __popcll(b0) + __popcll(b1) + __popcll(b2) + __popcll(b3);
      selbase += __popcll(c0) + __popcll(c1) + __popcll(c2) + __popcll(c3);
    }
    for (int off = 32; off > 0; off >>= 1) lz += __shfl_xor(lz, off, 64);
    const float rz = 1.f / lz;
    if (lane < HD) {
      float acc = 0.f;
#pragma unroll 4
      for (int p = 0; p < KSEL; ++p) {
        acc = fmaf(wb[w][p], V[((size_t)(b * N + idxb[w][p])) * TD + h * HD + lane], acc);
      }
      O[((size_t)(b * N + q0 + w)) * TD + h * HD + lane] = acc * rz;
    }
  } else {
    unsigned* ok = ckey + (((size_t)bhloc * N + q0 + w) * R + r) * KSEL;
    unsigned short* oi = cidx + (((size_t)bhloc * N + q0 + w) * R + r) * KSEL;
    int selbase = 0, eqbase = 0;
#pragma unroll
    for (int i = 0; i < NV4; ++i) {
      const int jb = r * RK + i * 256 + lane * 4;
      const unsigned u0 = kr[i].x, u1 = kr[i].y, u2 = kr[i].z, u3 = kr[i].w;
      const bool e0 = (u0 == kth), e1 = (u1 == kth), e2 = (u2 == kth), e3 = (u3 == kth);
      const unsigned long long b0 = __ballot(e0), b1 = __ballot(e1), b2 = __ballot(e2), b3 = __ballot(e3);
      const int eqlt = __popcll(b0 & lanelt) + __popcll(b1 & lanelt) + __popcll(b2 & lanelt) + __popcll(b3 & lanelt);
      int eo = 0;
      const bool s0 = (u0 > kth) || (e0 && (eqbase + eqlt + eo) < need_eq); eo += e0 ? 1 : 0;
      const bool s1 = (u1 > kth) || (e1 && (eqbase + eqlt + eo) < need_eq); eo += e1 ? 1 : 0;
      const bool s2 = (u2 > kth) || (e2 && (eqbase + eqlt + eo) < need_eq); eo += e2 ? 1 : 0;
      const bool s3 = (u3 > kth) || (e3 && (eqbase + eqlt + eo) < need_eq); eo += e3 ? 1 : 0;
      const unsigned long long c0 = __ballot(s0), c1 = __ballot(s1), c2 = __ballot(s2), c3 = __ballot(s3);
      const int sellt = __popcll(c0 & lanelt) + __popcll(c1 & lanelt) + __popcll(c2 & lanelt) + __popcll(c3 & lanelt);
      int so = 0;
      if (s0) { int p = selbase + sellt + so; ok[p] = u0; oi[p] = (unsigned short)(jb + 0); } so += s0 ? 1 : 0;
      if (s1) { int p = selbase + sellt + so; ok[p] = u1; oi[p] = (unsigned short)(jb + 1); } so += s1 ? 1 : 0;
      if (s2) { int p = selbase + sellt + so; ok[p] = u2; oi[p] = (unsigned short)(jb + 2); } so += s2 ? 1 : 0;
      if (s3) { int p = selbase + sellt + so; ok[p] = u3; oi[p] = (unsigned short)(jb + 3); } so += s3 ? 1 : 0;
      eqbase += __popcll(b0) + __popcll(b1) + __popcll(b2) + __popcll(b3);
      selbase += __popcll(c0) + __popcll(c1) + __popcll(c2) + __popcll(c3);
    }
  }
}

// ---------------- Stage B ----------------
template <int CN>
__global__ __launch_bounds__(256) void attnB_kernel(
    const unsigned* __restrict__ ckey, const unsigned short* __restrict__ cidx,
    const float* __restrict__ V, float* __restrict__ O, int N, int bh0) {
  constexpr int CL = CN / 64;
  __shared__ unsigned hist[4][256];
  __shared__ int idxb[4][KSEL];
  __shared__ float wb[4][KSEL];

  const int tid = threadIdx.x, w = tid >> 6, lane = tid & 63;
  const unsigned long long lanelt = (1ull << lane) - 1ull;
  const int g = blockIdx.x * 4 + w;
  const int bhloc = g / N;
  const int qi = g - bhloc * N;
  const int bh = bh0 + bhloc;
  const int b = bh >> 2, h = bh & 3;

  unsigned ck[CL], ci[CL];
#pragma unroll
  for (int i = 0; i < CL; ++i) {
    ck[i] = ckey[(size_t)g * CN + i * 64 + lane];
    ci[i] = cidx[(size_t)g * CN + i * 64 + lane];
  }

  unsigned mk = 0u;
#pragma unroll
  for (int i = 0; i < CL; ++i) mk = ck[i] > mk ? ck[i] : mk;
  for (int off = 32; off > 0; off >>= 1) {
    unsigned o = (unsigned)__shfl_xor((int)mk, off, 64);
    mk = o > mk ? o : mk;
  }
  const float mx = o2f(mk);

  unsigned* hw = hist[w];
  unsigned kth = 0u, mask = 0u;
  int rem = KSEL;
#pragma unroll
  for (int shift = 24; shift >= 0; shift -= 8) {
#pragma unroll
    for (int i = 0; i < 4; ++i) hw[lane + i * 64] = 0u;
#pragma unroll
    for (int i = 0; i < CL; ++i)
      if ((ck[i] & mask) == kth) atomicAdd(&hw[(ck[i] >> shift) & 255u], 1u);
    int v[4], loc = 0;
#pragma unroll
    for (int i = 0; i < 4; ++i) { v[i] = (int)hw[255 - (lane * 4 + i)]; loc += v[i]; }
    int incl = loc;
#pragma unroll
    for (int off = 1; off < 64; off <<= 1) {
      int t = __shfl_up(incl, off, 64);
      if (lane >= off) incl += t;
    }
    int c = incl - loc;
    int selidx = -1, selexcl = 0;
#pragma unroll
    for (int i = 0; i < 4; ++i) {
      if (selidx < 0 && rem > c && rem <= c + v[i]) {
        selidx = 255 - (lane * 4 + i); selexcl = c;
      }
      c += v[i];
    }
    unsigned long long vote = __ballot(selidx >= 0);
    int src = __ffsll((long long)vote) - 1;
    selidx = __shfl(selidx, src, 64);
    selexcl = __shfl(selexcl, src, 64);
    rem -= selexcl;
    kth |= ((unsigned)selidx << shift);
    mask |= (0xFFu << shift);
  }
  const int need_eq = rem;

  int selbase = 0, eqbase = 0;
  float lz = 0.f;
#pragma unroll
  for (int i = 0; i < CL; ++i) {
    const unsigned u = ck[i];
    const bool eq = (u == kth);
    const unsigned long long beq = __ballot(eq);
    const int eqrank = eqbase + __popcll(beq & lanelt);
    const bool sel = (u > kth) || (eq && eqrank < need_eq);
    const unsigned long long bsel = __ballot(sel);
    const int pos = selbase + __popcll(bsel & lanelt);
    if (sel) {
      float e = expf(o2f(u) - mx);
      idxb[w][pos] = (int)ci[i];
      wb[w][pos] = e;
      lz += e;
    }
    eqbase += __popcll(beq);
    selbase += __popcll(bsel);
  }
  for (int off = 32; off > 0; off >>= 1) lz += __shfl_xor(lz, off, 64);
  const float rz = 1.f / lz;

  if (lane < HD) {
    float acc = 0.f;
#pragma unroll 4
    for (int p = 0; p < KSEL; ++p) {
      acc = fmaf(wb[w][p], V[((size_t)(b * N + idxb[w][p])) * TD + h * HD + lane], acc);
    }
    O[((size_t)(b * N + qi)) * TD + h * HD + lane] = acc * rz;
  }
}

// out[b, t, n] = O[b, n, :] . ow[:, t] + ob[t]; 16-token tile (r11-proven).
#define OTOK 16
__global__ __launch_bounds__(256) void oproj_kernel(
    const float* __restrict__ O, const float* __restrict__ ow,
    const float* __restrict__ ob, float* __restrict__ out, int N) {
  __shared__ float otile[OTOK][TD + 1];
  const int tid = threadIdx.x;
  const int nt = N / OTOK;
  const int b = blockIdx.x / nt;
  const int n0 = (blockIdx.x % nt) * OTOK;
  const float* obase = O + ((size_t)(b * N + n0)) * TD;
  for (int idx = tid * 4; idx < OTOK * TD; idx += 1024) {
    float4 v = *reinterpret_cast<const float4*>(obase + idx);
    int r = idx / TD, c = idx - r * TD;
    otile[r][c] = v.x; otile[r][c + 1] = v.y; otile[r][c + 2] = v.z; otile[r][c + 3] = v.w;
  }
  __syncthreads();
  const int nl = tid & 15;
  const int ts = (tid >> 4) * 12;
  float a0 = 0.f, a1 = 0.f, a2 = 0.f, a3 = 0.f, a4 = 0.f, a5 = 0.f,
        a6 = 0.f, a7 = 0.f, a8 = 0.f, a9 = 0.f, a10 = 0.f, a11 = 0.f;
  for (int c = 0; c < TD; ++c) {
    float oval = otile[nl][c];
    const float* wr = ow + c * TD + ts;
    float4 w0 = *reinterpret_cast<const float4*>(wr);
    float4 w1 = *reinterpret_cast<const float4*>(wr + 4);
    float4 w2 = *reinterpret_cast<const float4*>(wr + 8);
    a0 = fmaf(oval, w0.x, a0); a1 = fmaf(oval, w0.y, a1);
    a2 = fmaf(oval, w0.z, a2); a3 = fmaf(oval, w0.w, a3);
    a4 = fmaf(oval, w1.x, a4); a5 = fmaf(oval, w1.y, a5);
    a6 = fmaf(oval, w1.z, a6); a7 = fmaf(oval, w1.w, a7);
    a8 = fmaf(oval, w2.x, a8); a9 = fmaf(oval, w2.y, a9);
    a10 = fmaf(oval, w2.z, a10); a11 = fmaf(oval, w2.w, a11);
  }
  const size_t ob2 = ((size_t)b * TD + ts) * N + n0 + nl;
  out[ob2 + 0 * N] = a0 + ob[ts + 0];
  out[ob2 + 1 * N] = a1 + ob[ts + 1];
  out[ob2 + 2 * N] = a2 + ob[ts + 2];
  out[ob2 + 3 * N] = a3 + ob[ts + 3];
  out[ob2 + 4 * N] = a4 + ob[ts + 4];
  out[ob2 + 5 * N] = a5 + ob[ts + 5];
  out[ob2 + 6 * N] = a6 + ob[ts + 6];
  out[ob2 + 7 * N] = a7 + ob[ts + 7];
  out[ob2 + 8 * N] = a8 + ob[ts + 8];
  out[ob2 + 9 * N] = a9 + ob[ts + 9];
  out[ob2 + 10 * N] = a10 + ob[ts + 10];
  out[ob2 + 11 * N] = a11 + ob[ts + 11];
}

extern "C" void kernel_launch(void* const* d_in, const int* in_sizes, int n_in,
                              void* d_out, int out_size, void* d_ws, size_t ws_size,
                              hipStream_t stream) {
  const int B = 2;
  const int Cs[3] = {64, 128, 192};
  const int Hs[3] = {64, 32, 16};
  const size_t out_off[3] = {0,
                             (size_t)2 * TD * 64 * 64,
                             (size_t)2 * TD * 64 * 64 + (size_t)2 * TD * 32 * 32};

  float* ws = (float*)d_ws;
  float* pe = ws;                                 // 3.1 MB
  float* Q = pe + (size_t)4096 * TD;              // each 6.3 MB
  float* Kt = Q + (size_t)B * 4096 * TD;
  float* V = Kt + (size_t)B * 4096 * TD;
  float* Obuf = V + (size_t)B * 4096 * TD;
  // lvl0 candidates for 2 (b,h) at a time: 2*4096 queries x 512 cand
  unsigned* ckey = (unsigned*)(Obuf + (size_t)B * 4096 * TD);               // 16.8 MB
  unsigned short* cidx = (unsigned short*)(ckey + (size_t)2 * 4096 * 512);  // 8.4 MB
  // total ws ~53.5 MB (r12/r13-proven)

  for (int lvl = 0; lvl < 3; ++lvl) {
    int C = Cs[lvl], H = Hs[lvl], W = H, N = H * W;
    const float* feat1 = (const float*)d_in[lvl * 2 + 0];
    const float* feat2 = (const float*)d_in[lvl * 2 + 1];
    const float* qw = (const float*)d_in[6 + lvl * 8 + 0];
    const float* qb = (const float*)d_in[6 + lvl * 8 + 1];
    const float* kw = (const float*)d_in[6 + lvl * 8 + 2];
    const float* kb = (const float*)d_in[6 + lvl * 8 + 3];
    const float* vw = (const float*)d_in[6 + lvl * 8 + 4];
    const float* vb = (const float*)d_in[6 + lvl * 8 + 5];
    const float* ow = (const float*)d_in[6 + lvl * 8 + 6];
    const float* ob = (const float*)d_in[6 + lvl * 8 + 7];

    pe_kernel<<<N, TD, 0, stream>>>(pe, W);
    dim3 gq(B * N / 64, 3);
    qkv_tiled<<<gq, 256, 0, stream>>>(feat1, feat2, qw, qb, kw, kb, vw, vb, pe, Q, Kt, V, C, N);

    if (N == 4096) {
      for (int g = 0; g < 4; ++g) {
        // 2 bh x 1024 qg x 4 ranges = 8192 blocks
        attnA_kernel<4096, 1024, false><<<8192, 256, 0, stream>>>(
            Q, Kt, ckey, cidx, V, Obuf, g * 2);
        attnB_kernel<512><<<2 * 4096 / 4, 256, 0, stream>>>(
            ckey, cidx, V, Obuf, 4096, g * 2);
      }
    } else if (N == 1024) {
      attnA_kernel<1024, 1024, true><<<8 * 256, 256, 0, stream>>>(
          Q, Kt, ckey, cidx, V, Obuf, 0);
    } else {
      attnA_kernel<256, 256, true><<<8 * 64, 256, 0, stream>>>(
          Q, Kt, ckey, cidx, V, Obuf, 0);
    }
    oproj_kernel<<<B * (N / OTOK), 256, 0, stream>>>(Obuf, ow, ob, (float*)d_out + out_off[lvl], N);
  }
}

// Round 15
// 891.801 us; speedup vs baseline: 2.3883x; 1.0888x over previous
//
#include <hip/hip_runtime.h>
#include <math.h>

#define TD 192
#define HD 48
#define KSEL 128
#define QB 4

// Map float to orderable unsigned: a > b (float) <=> f2o(a) > f2o(b)
__device__ __forceinline__ unsigned f2o(float f) {
  unsigned u = __float_as_uint(f);
  return (u & 0x80000000u) ? ~u : (u | 0x80000000u);
}
__device__ __forceinline__ float o2f(unsigned u) {
  unsigned v = (u & 0x80000000u) ? (u & 0x7fffffffu) : ~u;
  return __uint_as_float(v);
}

// 2D sinusoidal positional encoding, matches reference _pos_enc.
__global__ void pe_kernel(float* __restrict__ pe, int W) {
  int n = blockIdx.x;
  int t = threadIdx.x;                      // 0..191
  const float c = -0.09594104554885301f;    // -ln(10000)/96
  float val;
  if (t < 96) {
    float dv = expf((float)t * c);
    val = sinf((float)(n % W) * dv);
  } else {
    float dv = expf((float)(t - 96) * c);
    val = cosf((float)(n / W) * dv);
  }
  pe[n * TD + t] = val;
}

// Tiled QKV projection (r12-proven): 64 tokens x 192 channels per block.
__global__ __launch_bounds__(256) void qkv_tiled(
    const float* __restrict__ feat1, const float* __restrict__ feat2,
    const float* __restrict__ qw, const float* __restrict__ qb,
    const float* __restrict__ kw, const float* __restrict__ kb,
    const float* __restrict__ vw, const float* __restrict__ vb,
    const float* __restrict__ pe,
    float* __restrict__ Q, float* __restrict__ Kt, float* __restrict__ V,
    int C, int N) {
  __shared__ float ftile[64][64];
  const int type = blockIdx.y;
  const int tid = threadIdx.x;
  const int gtok = blockIdx.x * 64;
  const int b = gtok / N, n0 = gtok - b * N;
  const float* feat = (type == 0) ? feat1 : feat2;
  const float* wsel = (type == 0) ? qw : (type == 1) ? kw : vw;
  const float* bsel = (type == 0) ? qb : (type == 1) ? kb : vb;
  const int cg = tid >> 4, tg = tid & 15;
  const int ch0 = cg * 12, t0 = tg * 4;

  float4 z = make_float4(0.f, 0.f, 0.f, 0.f);
  float4 a0 = z, a1 = z, a2 = z, a3 = z, a4 = z, a5 = z,
         a6 = z, a7 = z, a8 = z, a9 = z, a10 = z, a11 = z;

  for (int c0 = 0; c0 < C; c0 += 64) {
#pragma unroll
    for (int rep = 0; rep < 4; ++rep) {
      int off = rep * 1024 + tid * 4;
      int r = off >> 6, cc = off & 63;
      *reinterpret_cast<float4*>(&ftile[r][cc]) =
          *reinterpret_cast<const float4*>(&feat[((size_t)(b * C + c0 + r)) * N + n0 + cc]);
    }
    __syncthreads();
#pragma unroll 8
    for (int k = 0; k < 64; ++k) {
      float4 f4 = *reinterpret_cast<const float4*>(&ftile[k][t0]);
      const float* wr = wsel + (size_t)(c0 + k) * TD + ch0;
      float4 w0 = *reinterpret_cast<const float4*>(wr);
      float4 w1 = *reinterpret_cast<const float4*>(wr + 4);
      float4 w2 = *reinterpret_cast<const float4*>(wr + 8);
#define QFMA(A, WS) A.x = fmaf(WS, f4.x, A.x); A.y = fmaf(WS, f4.y, A.y); \
                    A.z = fmaf(WS, f4.z, A.z); A.w = fmaf(WS, f4.w, A.w);
      QFMA(a0, w0.x) QFMA(a1, w0.y) QFMA(a2, w0.z) QFMA(a3, w0.w)
      QFMA(a4, w1.x) QFMA(a5, w1.y) QFMA(a6, w1.z) QFMA(a7, w1.w)
      QFMA(a8, w2.x) QFMA(a9, w2.y) QFMA(a10, w2.z) QFMA(a11, w2.w)
#undef QFMA
    }
    __syncthreads();
  }
  {
    float4 b0 = *reinterpret_cast<const float4*>(&bsel[ch0]);
    float4 b1 = *reinterpret_cast<const float4*>(&bsel[ch0 + 4]);
    float4 b2 = *reinterpret_cast<const float4*>(&bsel[ch0 + 8]);
#define BADD(A, S) A.x += S; A.y += S; A.z += S; A.w += S;
    BADD(a0, b0.x) BADD(a1, b0.y) BADD(a2, b0.z) BADD(a3, b0.w)
    BADD(a4, b1.x) BADD(a5, b1.y) BADD(a6, b1.z) BADD(a7, b1.w)
    BADD(a8, b2.x) BADD(a9, b2.y) BADD(a10, b2.z) BADD(a11, b2.w)
#undef BADD
  }
  if (type < 2) {
#define PEADD(F, TT) { \
    const float* pr = pe + (size_t)(n0 + t0 + (TT)) * TD + ch0; \
    float4 p0 = *reinterpret_cast<const float4*>(pr); \
    float4 p1 = *reinterpret_cast<const float4*>(pr + 4); \
    float4 p2 = *reinterpret_cast<const float4*>(pr + 8); \
    a0.F += p0.x; a1.F += p0.y; a2.F += p0.z; a3.F += p0.w; \
    a4.F += p1.x; a5.F += p1.y; a6.F += p1.z; a7.F += p1.w; \
    a8.F += p2.x; a9.F += p2.y; a10.F += p2.z; a11.F += p2.w; }
    PEADD(x, 0) PEADD(y, 1) PEADD(z, 2) PEADD(w, 3)
#undef PEADD
  }
  if (type == 1) {
#define KSTORE(A, CI) { int ch = ch0 + (CI); int h = ch / HD, d = ch - h * HD; \
    *reinterpret_cast<float4*>(&Kt[((size_t)(b * 4 + h) * HD + d) * N + n0 + t0]) = A; }
    KSTORE(a0, 0) KSTORE(a1, 1) KSTORE(a2, 2) KSTORE(a3, 3)
    KSTORE(a4, 4) KSTORE(a5, 5) KSTORE(a6, 6) KSTORE(a7, 7)
    KSTORE(a8, 8) KSTORE(a9, 9) KSTORE(a10, 10) KSTORE(a11, 11)
#undef KSTORE
  } else {
    float* out = (type == 0) ? Q : V;
#define RSTORE(F, TT) { \
    float* orow = out + (size_t)(b * N + n0 + t0 + (TT)) * TD + ch0; \
    *reinterpret_cast<float4*>(orow)     = make_float4(a0.F, a1.F, a2.F, a3.F); \
    *reinterpret_cast<float4*>(orow + 4) = make_float4(a4.F, a5.F, a6.F, a7.F); \
    *reinterpret_cast<float4*>(orow + 8) = make_float4(a8.F, a9.F, a10.F, a11.F); }
    RSTORE(x, 0) RSTORE(y, 1) RSTORE(z, 2) RSTORE(w, 3)
#undef RSTORE
  }
}

// ---------------- Stage A ----------------
// r14 structure + r15: (a) eq-fast-path compaction -- the final radix pass's
// selected-bin count IS the number of keys == kth; when it equals need_eq
// (always, for tie-free f32), sel = (u >= kth) exactly, skipping the eq-rank
// ballot machinery. (b) passes 2-4 use a single un-spread histogram copy
// (their predicated populations are tiny; only pass 1 needs the XOR-rotated
// 4-copy spread). FUSE (R==1): top-128 here IS global -> inline softmax+gather.
template <int N, int RK, bool FUSE>
__global__ __launch_bounds__(256) void attnA_kernel(
    const float* __restrict__ Q, const float* __restrict__ Kt,
    unsigned* __restrict__ ckey, unsigned short* __restrict__ cidx,
    const float* __restrict__ V, float* __restrict__ O, int bh0) {
  constexpr int R = N / RK;
  constexpr int NV4 = RK / 256;           // uint4 regs per lane (<=4)
  constexpr int nq = N / QB;
  constexpr int NCOPY = RK / 256;         // pass-1 histogram copies (1 or 4)
  __shared__ unsigned sb[QB * RK];        // keys; then per-wave histograms
  __shared__ float qv[QB][HD];

  const int tid = threadIdx.x;
  const int r = blockIdx.x % R;
  const int qg = (blockIdx.x / R) % nq;
  const int bhloc = blockIdx.x / (R * nq);
  const int bh = bh0 + bhloc;
  const int b = bh >> 2, h = bh & 3;
  const int q0 = qg * QB;
  const float scale = 0.14433756729740643f;  // 1/sqrt(48)

  if (tid < QB * HD) {
    int q = tid / HD, d = tid - q * HD;
    qv[q][d] = Q[((size_t)(b * N + q0 + q)) * TD + h * HD + d];
  }
  __syncthreads();

  const int w = tid >> 6, lane = tid & 63;
  const unsigned long long lanelt = (1ull << lane) - 1ull;
  const float* kt = Kt + ((size_t)(b * 4 + h) * HD) * N + r * RK;

  // ---- score GEMM for this range ----
  for (int j0 = tid * 4; j0 < RK; j0 += 1024) {
    float4 acc[QB];
#pragma unroll
    for (int q = 0; q < QB; ++q) acc[q] = make_float4(0.f, 0.f, 0.f, 0.f);
#pragma unroll
    for (int d4 = 0; d4 < HD; d4 += 4) {
      float4 k0 = *reinterpret_cast<const float4*>(kt + (size_t)(d4 + 0) * N + j0);
      float4 k1 = *reinterpret_cast<const float4*>(kt + (size_t)(d4 + 1) * N + j0);
      float4 k2 = *reinterpret_cast<const float4*>(kt + (size_t)(d4 + 2) * N + j0);
      float4 k3 = *reinterpret_cast<const float4*>(kt + (size_t)(d4 + 3) * N + j0);
#pragma unroll
      for (int q = 0; q < QB; ++q) {
        float4 qq = *reinterpret_cast<const float4*>(&qv[q][d4]);
        acc[q].x = fmaf(qq.x, k0.x, acc[q].x); acc[q].x = fmaf(qq.y, k1.x, acc[q].x);
        acc[q].x = fmaf(qq.z, k2.x, acc[q].x); acc[q].x = fmaf(qq.w, k3.x, acc[q].x);
        acc[q].y = fmaf(qq.x, k0.y, acc[q].y); acc[q].y = fmaf(qq.y, k1.y, acc[q].y);
        acc[q].y = fmaf(qq.z, k2.y, acc[q].y); acc[q].y = fmaf(qq.w, k3.y, acc[q].y);
        acc[q].z = fmaf(qq.x, k0.z, acc[q].z); acc[q].z = fmaf(qq.y, k1.z, acc[q].z);
        acc[q].z = fmaf(qq.z, k2.z, acc[q].z); acc[q].z = fmaf(qq.w, k3.z, acc[q].z);
        acc[q].w = fmaf(qq.x, k0.w, acc[q].w); acc[q].w = fmaf(qq.y, k1.w, acc[q].w);
        acc[q].w = fmaf(qq.z, k2.w, acc[q].w); acc[q].w = fmaf(qq.w, k3.w, acc[q].w);
      }
    }
#pragma unroll
    for (int q = 0; q < QB; ++q) {
      uint4 kk;
      kk.x = f2o(acc[q].x * scale); kk.y = f2o(acc[q].y * scale);
      kk.z = f2o(acc[q].z * scale); kk.w = f2o(acc[q].w * scale);
      *reinterpret_cast<uint4*>(&sb[q * RK + j0]) = kk;
    }
  }
  __syncthreads();

  // ---- per-wave: keys -> registers ----
  uint4 kr[NV4];
#pragma unroll
  for (int i = 0; i < NV4; ++i)
    kr[i] = *reinterpret_cast<const uint4*>(&sb[w * RK + i * 256 + lane * 4]);
  // Wave w now touches only sb[w*RK .. w*RK+RK) -> reuse as histograms.

  unsigned* h4 = sb + w * RK;
  const unsigned cb = ((unsigned)lane & (NCOPY - 1u)) << 8;   // copy base
  const unsigned cx = ((unsigned)lane & (NCOPY - 1u)) << 3;   // bank-rotate XOR

  // ---- radix select: 128th largest within range ----
  unsigned kth = 0u, mask = 0u;
  int rem = KSEL, eqcnt = 0;
#pragma unroll
  for (int shift = 24; shift >= 0; shift -= 8) {
    int v[4], loc = 0;
    if (shift == 24) {
      // pass 1 over ALL keys: NCOPY XOR-rotated copies (r14-proven)
#pragma unroll
      for (int i = 0; i < NCOPY; ++i)
        *reinterpret_cast<uint4*>(&h4[i * 256 + lane * 4]) = make_uint4(0, 0, 0, 0);
#pragma unroll
      for (int i = 0; i < NV4; ++i) {
        atomicAdd(&h4[cb + ((kr[i].x >> 24) ^ cx)], 1u);
        atomicAdd(&h4[cb + ((kr[i].y >> 24) ^ cx)], 1u);
        atomicAdd(&h4[cb + ((kr[i].z >> 24) ^ cx)], 1u);
        atomicAdd(&h4[cb + ((kr[i].w >> 24) ^ cx)], 1u);
      }
#pragma unroll
      for (int i = 0; i < 4; ++i) {
        unsigned bin = (unsigned)(255 - (lane * 4 + i));
        unsigned s = 0;
#pragma unroll
        for (int c = 0; c < NCOPY; ++c) s += h4[c * 256 + (bin ^ ((unsigned)c << 3))];
        v[i] = (int)s;
        loc += v[i];
      }
    } else {
      // passes 2-4: predicated population is tiny -> single copy, no spread
      *reinterpret_cast<uint4*>(&h4[lane * 4]) = make_uint4(0, 0, 0, 0);
#pragma unroll
      for (int i = 0; i < NV4; ++i) {
        if ((kr[i].x & mask) == kth) atomicAdd(&h4[(kr[i].x >> shift) & 255u], 1u);
        if ((kr[i].y & mask) == kth) atomicAdd(&h4[(kr[i].y >> shift) & 255u], 1u);
        if ((kr[i].z & mask) == kth) atomicAdd(&h4[(kr[i].z >> shift) & 255u], 1u);
        if ((kr[i].w & mask) == kth) atomicAdd(&h4[(kr[i].w >> shift) & 255u], 1u);
      }
#pragma unroll
      for (int i = 0; i < 4; ++i) { v[i] = (int)h4[255 - (lane * 4 + i)]; loc += v[i]; }
    }
    int incl = loc;
#pragma unroll
    for (int off = 1; off < 64; off <<= 1) {
      int t = __shfl_up(incl, off, 64);
      if (lane >= off) incl += t;
    }
    int c = incl - loc;
    int selidx = -1, selexcl = 0, selval = 0;
#pragma unroll
    for (int i = 0; i < 4; ++i) {
      if (selidx < 0 && rem > c && rem <= c + v[i]) {
        selidx = 255 - (lane * 4 + i); selexcl = c; selval = v[i];
      }
      c += v[i];
    }
    unsigned long long vote = __ballot(selidx >= 0);
    int src = __ffsll((long long)vote) - 1;
    selidx = __shfl(selidx, src, 64);
    selexcl = __shfl(selexcl, src, 64);
    eqcnt = __shfl(selval, src, 64);
    rem -= selexcl;
    kth |= ((unsigned)selidx << shift);
    mask |= (0xFFu << shift);
  }
  const int need_eq = rem;        // slots to take among ==kth, lowest index
  const bool simple = (eqcnt == need_eq);   // all eq keys selected (typical)

  if constexpr (FUSE) {
    unsigned mk = 0u;
#pragma unroll
    for (int i = 0; i < NV4; ++i) {
      unsigned a_ = kr[i].x > kr[i].y ? kr[i].x : kr[i].y;
      unsigned b_ = kr[i].z > kr[i].w ? kr[i].z : kr[i].w;
      a_ = a_ > b_ ? a_ : b_; mk = a_ > mk ? a_ : mk;
    }
    for (int off = 32; off > 0; off >>= 1) {
      unsigned o = (unsigned)__shfl_xor((int)mk, off, 64);
      mk = o > mk ? o : mk;
    }
    const float mx = o2f(mk);

    __shared__ int idxb[4][KSEL];
    __shared__ float wb[4][KSEL];
    float lz = 0.f;
    if (simple) {
      int selbase = 0;
#pragma unroll
      for (int i = 0; i < NV4; ++i) {
        const int jb = i * 256 + lane * 4;
        const unsigned u0 = kr[i].x, u1 = kr[i].y, u2 = kr[i].z, u3 = kr[i].w;
        const bool s0 = (u0 >= kth), s1 = (u1 >= kth), s2 = (u2 >= kth), s3 = (u3 >= kth);
        const unsigned long long c0 = __ballot(s0), c1 = __ballot(s1), c2 = __ballot(s2), c3 = __ballot(s3);
        const int sellt = __popcll(c0 & lanelt) + __popcll(c1 & lanelt) + __popcll(c2 & lanelt) + __popcll(c3 & lanelt);
        int so = 0;
        if (s0) { int p = selbase + sellt + so; float e = expf(o2f(u0) - mx); idxb[w][p] = jb + 0; wb[w][p] = e; lz += e; } so += s0 ? 1 : 0;
        if (s1) { int p = selbase + sellt + so; float e = expf(o2f(u1) - mx); idxb[w][p] = jb + 1; wb[w][p] = e; lz += e; } so += s1 ? 1 : 0;
        if (s2) { int p = selbase + sellt + so; float e = expf(o2f(u2) - mx); idxb[w][p] = jb + 2; wb[w][p] = e; lz += e; } so += s2 ? 1 : 0;
        if (s3) { int p = selbase + sellt + so; float e = expf(o2f(u3) - mx); idxb[w][p] = jb + 3; wb[w][p] = e; lz += e; } so += s3 ? 1 : 0;
        selbase += __popcll(c0) + __popcll(c1) + __popcll(c2) + __popcll(c3);
      }
    } else {
      int selbase = 0, eqbase = 0;
#pragma unroll
      for (int i = 0; i < NV4; ++i) {
        const int jb = i * 256 + lane * 4;
        const unsigned u0 = kr[i].x, u1 = kr[i].y, u2 = kr[i].z, u3 = kr[i].w;
        const bool e0 = (u0 == kth), e1 = (u1 == kth), e2 = (u2 == kth), e3 = (u3 == kth);
        const unsigned long long b0 = __ballot(e0), b1 = __ballot(e1), b2 = __ballot(e2), b3 = __ballot(e3);
        const int eqlt = __popcll(b0 & lanelt) + __popcll(b1 & lanelt) + __popcll(b2 & lanelt) + __popcll(b3 & lanelt);
        int eo = 0;
        const bool s0 = (u0 > kth) || (e0 && (eqbase + eqlt + eo) < need_eq); eo += e0 ? 1 : 0;
        const bool s1 = (u1 > kth) || (e1 && (eqbase + eqlt + eo) < need_eq); eo += e1 ? 1 : 0;
        const bool s2 = (u2 > kth) || (e2 && (eqbase + eqlt + eo) < need_eq); eo += e2 ? 1 : 0;
        const bool s3 = (u3 > kth) || (e3 && (eqbase + eqlt + eo) < need_eq); eo += e3 ? 1 : 0;
        const unsigned long long c0 = __ballot(s0), c1 = __ballot(s1), c2 = __ballot(s2), c3 = __ballot(s3);
        const int sellt = __popcll(c0 & lanelt) + __popcll(c1 & lanelt) + __popcll(c2 & lanelt) + __popcll(c3 & lanelt);
        int so = 0;
        if (s0) { int p = selbase + sellt + so; float e = expf(o2f(u0) - mx); idxb[w][p] = jb + 0; wb[w][p] = e; lz += e; } so += s0 ? 1 : 0;
        if (s1) { int p = selbase + sellt + so; float e = expf(o2f(u1) - mx); idxb[w][p] = jb + 1; wb[w][p] = e; lz += e; } so += s1 ? 1 : 0;
        if (s2) { int p = selbase + sellt + so; float e = expf(o2f(u2) - mx); idxb[w][p] = jb + 2; wb[w][p] = e; lz += e; } so += s2 ? 1 : 0;
        if (s3) { int p = selbase + sellt + so; float e = expf(o2f(u3) - mx); idxb[w][p] = jb + 3; wb[w][p] = e; lz += e; } so += s3 ? 1 : 0;
        eqbase += __popcll(b0) + __popcll(b1) + __popcll(b2) + __popcll(b3);
        selbase += __popcll(c0) + __popcll(c1) + __popcll(c2) + __popcll(c3);
      }
    }
    for (int off = 32; off > 0; off >>= 1) lz += __shfl_xor(lz, off, 64);
    const float rz = 1.f / lz;
    if (lane < HD) {
      float acc = 0.f;
#pragma unroll 4
      for (int p = 0; p < KSEL; ++p) {
        acc = fmaf(wb[w][p], V[((size_t)(b * N + idxb[w][p])) * TD + h * HD + lane], acc);
      }
      O[((size_t)(b * N + q0 + w)) * TD + h * HD + lane] = acc * rz;
    }
  } else {
    unsigned* ok = ckey + (((size_t)bhloc * N + q0 + w) * R + r) * KSEL;
    unsigned short* oi = cidx + (((size_t)bhloc * N + q0 + w) * R + r) * KSEL;
    if (simple) {
      int selbase = 0;
#pragma unroll
      for (int i = 0; i < NV4; ++i) {
        const int jb = r * RK + i * 256 + lane * 4;
        const unsigned u0 = kr[i].x, u1 = kr[i].y, u2 = kr[i].z, u3 = kr[i].w;
        const bool s0 = (u0 >= kth), s1 = (u1 >= kth), s2 = (u2 >= kth), s3 = (u3 >= kth);
        const unsigned long long c0 = __ballot(s0), c1 = __ballot(s1), c2 = __ballot(s2), c3 = __ballot(s3);
        const int sellt = __popcll(c0 & lanelt) + __popcll(c1 & lanelt) + __popcll(c2 & lanelt) + __popcll(c3 & lanelt);
        int so = 0;
        if (s0) { int p = selbase + sellt + so; ok[p] = u0; oi[p] = (unsigned short)(jb + 0); } so += s0 ? 1 : 0;
        if (s1) { int p = selbase + sellt + so; ok[p] = u1; oi[p] = (unsigned short)(jb + 1); } so += s1 ? 1 : 0;
        if (s2) { int p = selbase + sellt + so; ok[p] = u2; oi[p] = (unsigned short)(jb + 2); } so += s2 ? 1 : 0;
        if (s3) { int p = selbase + sellt + so; ok[p] = u3; oi[p] = (unsigned short)(jb + 3); } so += s3 ? 1 : 0;
        selbase += __popcll(c0) + __popcll(c1) + __popcll(c2) + __popcll(c3);
      }
    } else {
      int selbase = 0, eqbase = 0;
#pragma unroll
      for (int i = 0; i < NV4; ++i) {
        const int jb = r * RK + i * 256 + lane * 4;
        const unsigned u0 = kr[i].x, u1 = kr[i].y, u2 = kr[i].z, u3 = kr[i].w;
        const bool e0 = (u0 == kth), e1 = (u1 == kth), e2 = (u2 == kth), e3 = (u3 == kth);
        const unsigned long long b0 = __ballot(e0), b1 = __ballot(e1), b2 = __ballot(e2), b3 = __ballot(e3);
        const int eqlt = __popcll(b0 & lanelt) + __popcll(b1 & lanelt) + __popcll(b2 & lanelt) + __popcll(b3 & lanelt);
        int eo = 0;
        const bool s0 = (u0 > kth) || (e0 && (eqbase + eqlt + eo) < need_eq); eo += e0 ? 1 : 0;
        const bool s1 = (u1 > kth) || (e1 && (eqbase + eqlt + eo) < need_eq); eo += e1 ? 1 : 0;
        const bool s2 = (u2 > kth) || (e2 && (eqbase + eqlt + eo) < need_eq); eo += e2 ? 1 : 0;
        const bool s3 = (u3 > kth) || (e3 && (eqbase + eqlt + eo) < need_eq); eo += e3 ? 1 : 0;
        const unsigned long long c0 = __ballot(s0), c1 = __ballot(s1), c2 = __ballot(s2), c3 = __ballot(s3);
        const int sellt = __popcll(c0 & lanelt) + __popcll(c1 & lanelt) + __popcll(c2 & lanelt) + __popcll(c3 & lanelt);
        int so = 0;
        if (s0) { int p = selbase + sellt + so; ok[p] = u0; oi[p] = (unsigned short)(jb + 0); } so += s0 ? 1 : 0;
        if (s1) { int p = selbase + sellt + so; ok[p] = u1; oi[p] = (unsigned short)(jb + 1); } so += s1 ? 1 : 0;
        if (s2) { int p = selbase + sellt + so; ok[p] = u2; oi[p] = (unsigned short)(jb + 2); } so += s2 ? 1 : 0;
        if (s3) { int p = selbase + sellt + so; ok[p] = u3; oi[p] = (unsigned short)(jb + 3); } so += s3 ? 1 : 0;
        eqbase += __popcll(b0) + __popcll(b1) + __popcll(b2) + __popcll(b3);
        selbase += __popcll(c0) + __popcll(c1) + __popcll(c2) + __popcll(c3);
      }
    }
  }
}

// ---------------- Stage B ----------------
template <int CN>
__global__ __launch_bounds__(256) void attnB_kernel(
    const unsigned* __restrict__ ckey, const unsigned short* __restrict__ cidx,
    const float* __restrict__ V, float* __restrict__ O, int N, int bh0) {
  constexpr int CL = CN / 64;
  __shared__ unsigned hist[4][256];
  __shared__ int idxb[4][KSEL];
  __shared__ float wb[4][KSEL];

  const int tid = threadIdx.x, w = tid >> 6, lane = tid & 63;
  const unsigned long long lanelt = (1ull << lane) - 1ull;
  const int g = blockIdx.x * 4 + w;
  const int bhloc = g / N;
  const int qi = g - bhloc * N;
  const int bh = bh0 + bhloc;
  const int b = bh >> 2, h = bh & 3;

  unsigned ck[CL], ci[CL];
#pragma unroll
  for (int i = 0; i < CL; ++i) {
    ck[i] = ckey[(size_t)g * CN + i * 64 + lane];
    ci[i] = cidx[(size_t)g * CN + i * 64 + lane];
  }

  unsigned mk = 0u;
#pragma unroll
  for (int i = 0; i < CL; ++i) mk = ck[i] > mk ? ck[i] : mk;
  for (int off = 32; off > 0; off >>= 1) {
    unsigned o = (unsigned)__shfl_xor((int)mk, off, 64);
    mk = o > mk ? o : mk;
  }
  const float mx = o2f(mk);

  unsigned* hw = hist[w];
  unsigned kth = 0u, mask = 0u;
  int rem = KSEL, eqcnt = 0;
#pragma unroll
  for (int shift = 24; shift >= 0; shift -= 8) {
#pragma unroll
    for (int i = 0; i < 4; ++i) hw[lane + i * 64] = 0u;
#pragma unroll
    for (int i = 0; i < CL; ++i)
      if ((ck[i] & mask) == kth) atomicAdd(&hw[(ck[i] >> shift) & 255u], 1u);
    int v[4], loc = 0;
#pragma unroll
    for (int i = 0; i < 4; ++i) { v[i] = (int)hw[255 - (lane * 4 + i)]; loc += v[i]; }
    int incl = loc;
#pragma unroll
    for (int off = 1; off < 64; off <<= 1) {
      int t = __shfl_up(incl, off, 64);
      if (lane >= off) incl += t;
    }
    int c = incl - loc;
    int selidx = -1, selexcl = 0, selval = 0;
#pragma unroll
    for (int i = 0; i < 4; ++i) {
      if (selidx < 0 && rem > c && rem <= c + v[i]) {
        selidx = 255 - (lane * 4 + i); selexcl = c; selval = v[i];
      }
      c += v[i];
    }
    unsigned long long vote = __ballot(selidx >= 0);
    int src = __ffsll((long long)vote) - 1;
    selidx = __shfl(selidx, src, 64);
    selexcl = __shfl(selexcl, src, 64);
    eqcnt = __shfl(selval, src, 64);
    rem -= selexcl;
    kth |= ((unsigned)selidx << shift);
    mask |= (0xFFu << shift);
  }
  const int need_eq = rem;
  const bool simple = (eqcnt == need_eq);

  float lz = 0.f;
  if (simple) {
    int selbase = 0;
#pragma unroll
    for (int i = 0; i < CL; ++i) {
      const unsigned u = ck[i];
      const bool sel = (u >= kth);
      const unsigned long long bsel = __ballot(sel);
      const int pos = selbase + __popcll(bsel & lanelt);
      if (sel) {
        float e = expf(o2f(u) - mx);
        idxb[w][pos] = (int)ci[i];
        wb[w][pos] = e;
        lz += e;
      }
      selbase += __popcll(bsel);
    }
  } else {
    int selbase = 0, eqbase = 0;
#pragma unroll
    for (int i = 0; i < CL; ++i) {
      const unsigned u = ck[i];
      const bool eq = (u == kth);
      const unsigned long long beq = __ballot(eq);
      const int eqrank = eqbase + __popcll(beq & lanelt);
      const bool sel = (u > kth) || (eq && eqrank < need_eq);
      const unsigned long long bsel = __ballot(sel);
      const int pos = selbase + __popcll(bsel & lanelt);
      if (sel) {
        float e = expf(o2f(u) - mx);
        idxb[w][pos] = (int)ci[i];
        wb[w][pos] = e;
        lz += e;
      }
      eqbase += __popcll(beq);
      selbase += __popcll(bsel);
    }
  }
  for (int off = 32; off > 0; off >>= 1) lz += __shfl_xor(lz, off, 64);
  const float rz = 1.f / lz;

  if (lane < HD) {
    float acc = 0.f;
#pragma unroll 4
    for (int p = 0; p < KSEL; ++p) {
      acc = fmaf(wb[w][p], V[((size_t)(b * N + idxb[w][p])) * TD + h * HD + lane], acc);
    }
    O[((size_t)(b * N + qi)) * TD + h * HD + lane] = acc * rz;
  }
}

// out[b, t, n] = O[b, n, :] . ow[:, t] + ob[t]; 16-token tile (r11-proven).
#define OTOK 16
__global__ __launch_bounds__(256) void oproj_kernel(
    const float* __restrict__ O, const float* __restrict__ ow,
    const float* __restrict__ ob, float* __restrict__ out, int N) {
  __shared__ float otile[OTOK][TD + 1];
  const int tid = threadIdx.x;
  const int nt = N / OTOK;
  const int b = blockIdx.x / nt;
  const int n0 = (blockIdx.x % nt) * OTOK;
  const float* obase = O + ((size_t)(b * N + n0)) * TD;
  for (int idx = tid * 4; idx < OTOK * TD; idx += 1024) {
    float4 v = *reinterpret_cast<const float4*>(obase + idx);
    int r = idx / TD, c = idx - r * TD;
    otile[r][c] = v.x; otile[r][c + 1] = v.y; otile[r][c + 2] = v.z; otile[r][c + 3] = v.w;
  }
  __syncthreads();
  const int nl = tid & 15;
  const int ts = (tid >> 4) * 12;
  float a0 = 0.f, a1 = 0.f, a2 = 0.f, a3 = 0.f, a4 = 0.f, a5 = 0.f,
        a6 = 0.f, a7 = 0.f, a8 = 0.f, a9 = 0.f, a10 = 0.f, a11 = 0.f;
  for (int c = 0; c < TD; ++c) {
    float oval = otile[nl][c];
    const float* wr = ow + c * TD + ts;
    float4 w0 = *reinterpret_cast<const float4*>(wr);
    float4 w1 = *reinterpret_cast<const float4*>(wr + 4);
    float4 w2 = *reinterpret_cast<const float4*>(wr + 8);
    a0 = fmaf(oval, w0.x, a0); a1 = fmaf(oval, w0.y, a1);
    a2 = fmaf(oval, w0.z, a2); a3 = fmaf(oval, w0.w, a3);
    a4 = fmaf(oval, w1.x, a4); a5 = fmaf(oval, w1.y, a5);
    a6 = fmaf(oval, w1.z, a6); a7 = fmaf(oval, w1.w, a7);
    a8 = fmaf(oval, w2.x, a8); a9 = fmaf(oval, w2.y, a9);
    a10 = fmaf(oval, w2.z, a10); a11 = fmaf(oval, w2.w, a11);
  }
  const size_t ob2 = ((size_t)b * TD + ts) * N + n0 + nl;
  out[ob2 + 0 * N] = a0 + ob[ts + 0];
  out[ob2 + 1 * N] = a1 + ob[ts + 1];
  out[ob2 + 2 * N] = a2 + ob[ts + 2];
  out[ob2 + 3 * N] = a3 + ob[ts + 3];
  out[ob2 + 4 * N] = a4 + ob[ts + 4];
  out[ob2 + 5 * N] = a5 + ob[ts + 5];
  out[ob2 + 6 * N] = a6 + ob[ts + 6];
  out[ob2 + 7 * N] = a7 + ob[ts + 7];
  out[ob2 + 8 * N] = a8 + ob[ts + 8];
  out[ob2 + 9 * N] = a9 + ob[ts + 9];
  out[ob2 + 10 * N] = a10 + ob[ts + 10];
  out[ob2 + 11 * N] = a11 + ob[ts + 11];
}

extern "C" void kernel_launch(void* const* d_in, const int* in_sizes, int n_in,
                              void* d_out, int out_size, void* d_ws, size_t ws_size,
                              hipStream_t stream) {
  const int B = 2;
  const int Cs[3] = {64, 128, 192};
  const int Hs[3] = {64, 32, 16};
  const size_t out_off[3] = {0,
                             (size_t)2 * TD * 64 * 64,
                             (size_t)2 * TD * 64 * 64 + (size_t)2 * TD * 32 * 32};

  float* ws = (float*)d_ws;
  float* pe = ws;
  float* Q = pe + (size_t)4096 * TD;
  float* Kt = Q + (size_t)B * 4096 * TD;
  float* V = Kt + (size_t)B * 4096 * TD;
  float* Obuf = V + (size_t)B * 4096 * TD;
  unsigned* ckey = (unsigned*)(Obuf + (size_t)B * 4096 * TD);

  // lvl0 candidate batching: 4 (b,h) per round if workspace allows, else 2.
  // fixed buffers = 28.3 MB; GBH=4 adds 50.4 MB (78.7 total), GBH=2 adds
  // 25.2 MB (53.5 total, r12-r14-proven).
  const size_t base_floats = (size_t)4096 * TD * (1 + 4 * B);
  const size_t need4 = base_floats * 4 + (size_t)4 * 4096 * 512 * 6 + (1 << 20);
  const int GBH = (ws_size >= need4) ? 4 : 2;
  unsigned short* cidx = (unsigned short*)(ckey + (size_t)GBH * 4096 * 512);

  for (int lvl = 0; lvl < 3; ++lvl) {
    int C = Cs[lvl], H = Hs[lvl], W = H, N = H * W;
    const float* feat1 = (const float*)d_in[lvl * 2 + 0];
    const float* feat2 = (const float*)d_in[lvl * 2 + 1];
    const float* qw = (const float*)d_in[6 + lvl * 8 + 0];
    const float* qb = (const float*)d_in[6 + lvl * 8 + 1];
    const float* kw = (const float*)d_in[6 + lvl * 8 + 2];
    const float* kb = (const float*)d_in[6 + lvl * 8 + 3];
    const float* vw = (const float*)d_in[6 + lvl * 8 + 4];
    const float* vb = (const float*)d_in[6 + lvl * 8 + 5];
    const float* ow = (const float*)d_in[6 + lvl * 8 + 6];
    const float* ob = (const float*)d_in[6 + lvl * 8 + 7];

    pe_kernel<<<N, TD, 0, stream>>>(pe, W);
    dim3 gq(B * N / 64, 3);
    qkv_tiled<<<gq, 256, 0, stream>>>(feat1, feat2, qw, qb, kw, kb, vw, vb, pe, Q, Kt, V, C, N);

    if (N == 4096) {
      for (int g = 0; g < 8 / GBH; ++g) {
        attnA_kernel<4096, 1024, false><<<GBH * 4096, 256, 0, stream>>>(
            Q, Kt, ckey, cidx, V, Obuf, g * GBH);
        attnB_kernel<512><<<GBH * 1024, 256, 0, stream>>>(
            ckey, cidx, V, Obuf, 4096, g * GBH);
      }
    } else if (N == 1024) {
      attnA_kernel<1024, 1024, true><<<8 * 256, 256, 0, stream>>>(
          Q, Kt, ckey, cidx, V, Obuf, 0);
    } else {
      attnA_kernel<256, 256, true><<<8 * 64, 256, 0, stream>>>(
          Q, Kt, ckey, cidx, V, Obuf, 0);
    }
    oproj_kernel<<<B * (N / OTOK), 256, 0, stream>>>(Obuf, ow, ob, (float*)d_out + out_off[lvl], N);
  }
}